// Round 1
// baseline (1839.947 us; speedup 1.0000x reference)
//
#include <hip/hip_runtime.h>

#define N_NODES 100000
#define N_EDGES 1600000
#define D 128
#define N_GRAPHS 64
#define BN_EPS 1e-5f

// ---------------- CSR build (dst-keyed) ----------------
__global__ void k_hist(const int* __restrict__ dst, int* __restrict__ deg) {
  int i = blockIdx.x * blockDim.x + threadIdx.x;
  if (i < N_EDGES) atomicAdd(&deg[dst[i]], 1);
}

__global__ __launch_bounds__(1024) void k_scan(const int* __restrict__ deg,
                                               int* __restrict__ off,
                                               int* __restrict__ cur) {
  __shared__ int ls[1024];
  const int CH = (N_NODES + 1023) / 1024; // 98
  int t = threadIdx.x;
  int c0 = t * CH;
  int c1 = min(c0 + CH, N_NODES);
  int s = 0;
  for (int i = c0; i < c1; i++) s += deg[i];
  ls[t] = s;
  __syncthreads();
  for (int o = 1; o < 1024; o <<= 1) {
    int v = (t >= o) ? ls[t - o] : 0;
    __syncthreads();
    ls[t] += v;
    __syncthreads();
  }
  int run = (t == 0) ? 0 : ls[t - 1];
  for (int i = c0; i < c1; i++) { off[i] = run; cur[i] = run; run += deg[i]; }
  if (t == 0) off[N_NODES] = N_EDGES;
}

__global__ void k_place(const int* __restrict__ ei, int* __restrict__ cur,
                        int* __restrict__ esrc) {
  int i = blockIdx.x * blockDim.x + threadIdx.x;
  if (i < N_EDGES) {
    int s = ei[i];            // src
    int d = ei[N_EDGES + i];  // dst
    int p = atomicAdd(&cur[d], 1);
    esrc[p] = s;
  }
}

// ---------------- agg + (1+eps)*h fuse ----------------
__global__ __launch_bounds__(128) void k_aggz(const float* __restrict__ h,
                                              const int* __restrict__ off,
                                              const int* __restrict__ esrc,
                                              const float* __restrict__ epsp,
                                              float* __restrict__ z) {
  int n = blockIdx.x;
  int f = threadIdx.x;
  float e = 1.0f + epsp[0];
  int o0 = off[n], o1 = off[n + 1];
  float acc = e * h[(long)n * D + f];
  for (int j = o0; j < o1; j++) {
    int s = esrc[j];
    acc += h[(long)s * D + f];
  }
  z[(long)n * D + f] = acc;
}

// ---------------- GEMM: out[M x 128] = T(in) @ W, T = identity (MODE 0)
//                  or BN+ReLU (MODE 1) applied to the input on tile load
template <int MODE>
__global__ __launch_bounds__(256) void k_gemm(const float* __restrict__ in,
                                              const float* __restrict__ W,
                                              float* __restrict__ out,
                                              const float* __restrict__ mu,
                                              const float* __restrict__ rs,
                                              const float* __restrict__ gamma,
                                              const float* __restrict__ beta) {
  __shared__ float Zs[64][132];   // pad to 132: float4-aligned, conflict-free
  __shared__ float Ws[32][128];
  const int t = threadIdx.x;
  const int row0 = blockIdx.x * 64;

  // load Z tile (64 x 128) with optional BN+ReLU transform
#pragma unroll
  for (int i = 0; i < 8; i++) {
    int q = t + i * 256;
    int r = q >> 5, c = (q & 31) << 2;
    int grow = row0 + r;
    float4 v = make_float4(0.f, 0.f, 0.f, 0.f);
    if (grow < N_NODES) {
      v = *(const float4*)(in + (long)grow * D + c);
      if (MODE == 1) {
        v.x = fmaxf(fmaf((v.x - mu[c]) * rs[c], gamma[c], beta[c]), 0.f);
        v.y = fmaxf(fmaf((v.y - mu[c + 1]) * rs[c + 1], gamma[c + 1], beta[c + 1]), 0.f);
        v.z = fmaxf(fmaf((v.z - mu[c + 2]) * rs[c + 2], gamma[c + 2], beta[c + 2]), 0.f);
        v.w = fmaxf(fmaf((v.w - mu[c + 3]) * rs[c + 3], gamma[c + 3], beta[c + 3]), 0.f);
      }
    }
    *(float4*)&Zs[r][c] = v;
  }

  float acc[4][8];
#pragma unroll
  for (int r = 0; r < 4; r++)
#pragma unroll
    for (int c = 0; c < 8; c++) acc[r][c] = 0.f;

  const int rg = (t >> 4) << 2;   // row base within tile (0..60)
  const int cg = (t & 15) << 3;   // col base (0..120)

  for (int kc = 0; kc < D; kc += 32) {
#pragma unroll
    for (int i = 0; i < 4; i++) {
      int q = t + i * 256;
      int kr = q >> 5, c = (q & 31) << 2;
      *(float4*)&Ws[kr][c] = *(const float4*)(W + (long)(kc + kr) * D + c);
    }
    __syncthreads();
#pragma unroll
    for (int k = 0; k < 32; k++) {
      float a0 = Zs[rg + 0][kc + k];
      float a1 = Zs[rg + 1][kc + k];
      float a2 = Zs[rg + 2][kc + k];
      float a3 = Zs[rg + 3][kc + k];
      float4 b0 = *(float4*)&Ws[k][cg];
      float4 b1 = *(float4*)&Ws[k][cg + 4];
      acc[0][0] = fmaf(a0, b0.x, acc[0][0]); acc[0][1] = fmaf(a0, b0.y, acc[0][1]);
      acc[0][2] = fmaf(a0, b0.z, acc[0][2]); acc[0][3] = fmaf(a0, b0.w, acc[0][3]);
      acc[0][4] = fmaf(a0, b1.x, acc[0][4]); acc[0][5] = fmaf(a0, b1.y, acc[0][5]);
      acc[0][6] = fmaf(a0, b1.z, acc[0][6]); acc[0][7] = fmaf(a0, b1.w, acc[0][7]);
      acc[1][0] = fmaf(a1, b0.x, acc[1][0]); acc[1][1] = fmaf(a1, b0.y, acc[1][1]);
      acc[1][2] = fmaf(a1, b0.z, acc[1][2]); acc[1][3] = fmaf(a1, b0.w, acc[1][3]);
      acc[1][4] = fmaf(a1, b1.x, acc[1][4]); acc[1][5] = fmaf(a1, b1.y, acc[1][5]);
      acc[1][6] = fmaf(a1, b1.z, acc[1][6]); acc[1][7] = fmaf(a1, b1.w, acc[1][7]);
      acc[2][0] = fmaf(a2, b0.x, acc[2][0]); acc[2][1] = fmaf(a2, b0.y, acc[2][1]);
      acc[2][2] = fmaf(a2, b0.z, acc[2][2]); acc[2][3] = fmaf(a2, b0.w, acc[2][3]);
      acc[2][4] = fmaf(a2, b1.x, acc[2][4]); acc[2][5] = fmaf(a2, b1.y, acc[2][5]);
      acc[2][6] = fmaf(a2, b1.z, acc[2][6]); acc[2][7] = fmaf(a2, b1.w, acc[2][7]);
      acc[3][0] = fmaf(a3, b0.x, acc[3][0]); acc[3][1] = fmaf(a3, b0.y, acc[3][1]);
      acc[3][2] = fmaf(a3, b0.z, acc[3][2]); acc[3][3] = fmaf(a3, b0.w, acc[3][3]);
      acc[3][4] = fmaf(a3, b1.x, acc[3][4]); acc[3][5] = fmaf(a3, b1.y, acc[3][5]);
      acc[3][6] = fmaf(a3, b1.z, acc[3][6]); acc[3][7] = fmaf(a3, b1.w, acc[3][7]);
    }
    __syncthreads();
  }

#pragma unroll
  for (int r = 0; r < 4; r++) {
    int grow = row0 + rg + r;
    if (grow < N_NODES) {
      float4 o0 = make_float4(acc[r][0], acc[r][1], acc[r][2], acc[r][3]);
      float4 o1 = make_float4(acc[r][4], acc[r][5], acc[r][6], acc[r][7]);
      *(float4*)(out + (long)grow * D + cg) = o0;
      *(float4*)(out + (long)grow * D + cg + 4) = o1;
    }
  }
}

// ---------------- BN column stats ----------------
__global__ __launch_bounds__(256) void k_stats(const float* __restrict__ y,
                                               float* __restrict__ ssum,
                                               float* __restrict__ ssq) {
  int f = threadIdx.x & 127;
  int rr = threadIdx.x >> 7;
  float s = 0.f, q = 0.f;
  for (int row = blockIdx.x * 2 + rr; row < N_NODES; row += gridDim.x * 2) {
    float v = y[(long)row * D + f];
    s += v;
    q = fmaf(v, v, q);
  }
  __shared__ float Ls[256], Lq[256];
  Ls[threadIdx.x] = s; Lq[threadIdx.x] = q;
  __syncthreads();
  if (rr == 0) {
    s += Ls[threadIdx.x + 128];
    q += Lq[threadIdx.x + 128];
    atomicAdd(&ssum[f], s);
    atomicAdd(&ssq[f], q);
  }
}

__global__ void k_bnfin(const float* __restrict__ ssum, const float* __restrict__ ssq,
                        float* __restrict__ mu, float* __restrict__ rs) {
  int f = threadIdx.x;
  float m = ssum[f] * (1.0f / (float)N_NODES);
  float v = ssq[f] * (1.0f / (float)N_NODES) - m * m;
  mu[f] = m;
  rs[f] = rsqrtf(v + BN_EPS);
}

// ---------------- BN2 + ReLU elementwise ----------------
__global__ void k_ew(const float* __restrict__ y, const float* __restrict__ mu,
                     const float* __restrict__ rs, const float* __restrict__ gamma,
                     const float* __restrict__ beta, float* __restrict__ out) {
  long i = (long)(blockIdx.x * blockDim.x + threadIdx.x) * 4;
  if (i >= (long)N_NODES * D) return;
  int c = (int)(i & 127);
  float4 v = *(const float4*)(y + i);
  v.x = fmaxf(fmaf((v.x - mu[c]) * rs[c], gamma[c], beta[c]), 0.f);
  v.y = fmaxf(fmaf((v.y - mu[c + 1]) * rs[c + 1], gamma[c + 1], beta[c + 1]), 0.f);
  v.z = fmaxf(fmaf((v.z - mu[c + 2]) * rs[c + 2], gamma[c + 2], beta[c + 2]), 0.f);
  v.w = fmaxf(fmaf((v.w - mu[c + 3]) * rs[c + 3], gamma[c + 3], beta[c + 3]), 0.f);
  *(float4*)(out + i) = v;
}

// ---------------- graph readout ----------------
#define RCH 512
__global__ __launch_bounds__(128) void k_readout(const float* __restrict__ h,
                                                 const int* __restrict__ batch,
                                                 float* __restrict__ gsum,
                                                 int* __restrict__ gcnt) {
  int start = blockIdx.x * RCH;
  int end = min(start + RCH, N_NODES);
  if (start >= end) return;
  int f = threadIdx.x;
  float acc = 0.f;
  int cnt = 0;
  int curg = batch[start];
  for (int n = start; n < end; n++) {
    int g = batch[n];
    if (g != curg) {
      atomicAdd(&gsum[curg * D + f], acc);
      if (f == 0) atomicAdd(&gcnt[curg], cnt);
      acc = 0.f; cnt = 0; curg = g;
    }
    acc += h[(long)n * D + f];
    cnt++;
  }
  atomicAdd(&gsum[curg * D + f], acc);
  if (f == 0) atomicAdd(&gcnt[curg], cnt);
}

__global__ __launch_bounds__(128) void k_gnorm(const float* __restrict__ gsum,
                                               const int* __restrict__ gcnt,
                                               float* __restrict__ out) {
  __shared__ float red[128];
  int g = blockIdx.x, f = threadIdx.x;
  float c = (float)gcnt[g];
  float v = gsum[g * D + f] / fmaxf(c, 1.0f);
  red[f] = v * v;
  __syncthreads();
  for (int o = 64; o > 0; o >>= 1) {
    if (f < o) red[f] += red[f + o];
    __syncthreads();
  }
  float nrm = sqrtf(red[0]);
  out[(long)g * D + f] = v / fmaxf(nrm, 1e-12f);
}

extern "C" void kernel_launch(void* const* d_in, const int* in_sizes, int n_in,
                              void* d_out, int out_size, void* d_ws, size_t ws_size,
                              hipStream_t stream) {
  const float* x   = (const float*)d_in[0];
  const int*   ei  = (const int*)d_in[1];
  const int*   bat = (const int*)d_in[2];
  const float* W1  = (const float*)d_in[3];
  const float* g1  = (const float*)d_in[4];
  const float* b1  = (const float*)d_in[5];
  const float* W2  = (const float*)d_in[6];
  const float* g2  = (const float*)d_in[7];
  const float* b2  = (const float*)d_in[8];
  const float* eps = (const float*)d_in[9];
  float* out = (float*)d_out;

  char* w = (char*)d_ws;
  float* bufA = (float*)w; w += (size_t)N_NODES * D * 4;
  float* bufB = (float*)w; w += (size_t)N_NODES * D * 4;
  int* deg  = (int*)w; w += 400016;
  int* off  = (int*)w; w += 400016;
  int* cur  = (int*)w; w += 400016;
  int* esrc = (int*)w; w += (size_t)N_EDGES * 4;
  float* ssum = (float*)w; w += 512;
  float* ssq  = (float*)w; w += 512;
  float* mu   = (float*)w; w += 512;
  float* rs   = (float*)w; w += 512;
  float* gsum = (float*)w; w += (size_t)N_GRAPHS * D * 4;
  int* gcnt   = (int*)w; w += 256;

  // build CSR once (edge_index is layer-invariant)
  hipMemsetAsync(deg, 0, (size_t)N_NODES * 4, stream);
  k_hist<<<(N_EDGES + 255) / 256, 256, 0, stream>>>(ei + N_EDGES, deg);
  k_scan<<<1, 1024, 0, stream>>>(deg, off, cur);
  k_place<<<(N_EDGES + 255) / 256, 256, 0, stream>>>(ei, cur, esrc);

  const int gemm_grid = (N_NODES + 63) / 64;
  const float* h = x;
  for (int l = 0; l < 3; l++) {
    k_aggz<<<N_NODES, 128, 0, stream>>>(h, off, esrc, eps + l, bufA);
    k_gemm<0><<<gemm_grid, 256, 0, stream>>>(bufA, W1 + (size_t)l * D * D, bufB,
                                             nullptr, nullptr, nullptr, nullptr);
    hipMemsetAsync(ssum, 0, 1024, stream);  // ssum + ssq contiguous
    k_stats<<<512, 256, 0, stream>>>(bufB, ssum, ssq);
    k_bnfin<<<1, 128, 0, stream>>>(ssum, ssq, mu, rs);
    k_gemm<1><<<gemm_grid, 256, 0, stream>>>(bufB, W2 + (size_t)l * D * D, bufA,
                                             mu, rs, g1 + l * D, b1 + l * D);
    hipMemsetAsync(ssum, 0, 1024, stream);
    k_stats<<<512, 256, 0, stream>>>(bufA, ssum, ssq);
    k_bnfin<<<1, 128, 0, stream>>>(ssum, ssq, mu, rs);
    k_ew<<<(N_NODES * D / 4 + 255) / 256, 256, 0, stream>>>(bufA, mu, rs,
                                                            g2 + l * D, b2 + l * D, out);
    h = out;
  }

  hipMemsetAsync(gsum, 0, (size_t)N_GRAPHS * D * 4, stream);
  hipMemsetAsync(gcnt, 0, (size_t)N_GRAPHS * 4, stream);
  k_readout<<<(N_NODES + RCH - 1) / RCH, 128, 0, stream>>>(out, bat, gsum, gcnt);
  k_gnorm<<<N_GRAPHS, 128, 0, stream>>>(gsum, gcnt, out + (size_t)N_NODES * D);
}

// Round 2
// 1426.701 us; speedup vs baseline: 1.2897x; 1.2897x over previous
//
#include <hip/hip_runtime.h>

#define N_NODES 100000
#define N_EDGES 1600000
#define D 128
#define N_GRAPHS 64
#define BN_EPS 1e-5f

// ---------------- CSR build (dst-keyed) ----------------
__global__ void k_hist(const int* __restrict__ dst, int* __restrict__ deg) {
  int i = blockIdx.x * blockDim.x + threadIdx.x;
  if (i < N_EDGES) atomicAdd(&deg[dst[i]], 1);
}

#define SCAN_CH 512
#define SCAN_NB ((N_NODES + SCAN_CH - 1) / SCAN_CH)  // 196

__global__ __launch_bounds__(256) void k_scan1(const int* __restrict__ deg,
                                               int* __restrict__ bsum) {
  __shared__ int ls[256];
  int base = blockIdx.x * SCAN_CH;
  int t = threadIdx.x;
  int s = 0;
  for (int i = t; i < SCAN_CH; i += 256) {
    int idx = base + i;
    if (idx < N_NODES) s += deg[idx];
  }
  ls[t] = s;
  __syncthreads();
  for (int o = 128; o > 0; o >>= 1) {
    if (t < o) ls[t] += ls[t + o];
    __syncthreads();
  }
  if (t == 0) bsum[blockIdx.x] = ls[0];
}

__global__ __launch_bounds__(256) void k_scan2(const int* __restrict__ bsum,
                                               int* __restrict__ bpre) {
  __shared__ int ls[256];
  int t = threadIdx.x;
  int v = (t < SCAN_NB) ? bsum[t] : 0;
  ls[t] = v;
  __syncthreads();
  for (int o = 1; o < 256; o <<= 1) {
    int u = (t >= o) ? ls[t - o] : 0;
    __syncthreads();
    ls[t] += u;
    __syncthreads();
  }
  if (t < SCAN_NB) bpre[t] = ls[t] - v;  // exclusive
}

__global__ __launch_bounds__(256) void k_scan3(const int* __restrict__ deg,
                                               const int* __restrict__ bpre,
                                               int* __restrict__ off,
                                               int* __restrict__ cur) {
  __shared__ int ls[256];
  int base = blockIdx.x * SCAN_CH;
  int t = threadIdx.x;
  int i0 = base + t * 2;
  int d0 = (i0 < N_NODES) ? deg[i0] : 0;
  int d1 = (i0 + 1 < N_NODES) ? deg[i0 + 1] : 0;
  int s = d0 + d1;
  ls[t] = s;
  __syncthreads();
  for (int o = 1; o < 256; o <<= 1) {
    int u = (t >= o) ? ls[t - o] : 0;
    __syncthreads();
    ls[t] += u;
    __syncthreads();
  }
  int pre = bpre[blockIdx.x] + ls[t] - s;
  if (i0 < N_NODES) { off[i0] = pre; cur[i0] = pre; }
  if (i0 + 1 < N_NODES) { off[i0 + 1] = pre + d0; cur[i0 + 1] = pre + d0; }
  if (blockIdx.x == 0 && t == 0) off[N_NODES] = N_EDGES;
}

__global__ void k_place(const int* __restrict__ ei, int* __restrict__ cur,
                        int* __restrict__ esrc) {
  int i = blockIdx.x * blockDim.x + threadIdx.x;
  if (i < N_EDGES) {
    int s = ei[i];
    int d = ei[N_EDGES + i];
    int p = atomicAdd(&cur[d], 1);
    esrc[p] = s;
  }
}

// ---------------- agg + (1+eps)*h, optional BN+ReLU on gathered rows --------
__device__ inline float4 bn_relu4(float4 v, float4 m, float4 r, float4 g, float4 b) {
  v.x = fmaxf(fmaf((v.x - m.x) * r.x, g.x, b.x), 0.f);
  v.y = fmaxf(fmaf((v.y - m.y) * r.y, g.y, b.y), 0.f);
  v.z = fmaxf(fmaf((v.z - m.z) * r.z, g.z, b.z), 0.f);
  v.w = fmaxf(fmaf((v.w - m.w) * r.w, g.w, b.w), 0.f);
  return v;
}

template <int MODE>
__global__ __launch_bounds__(256) void k_aggz(const float* __restrict__ h,
                                              const int* __restrict__ off,
                                              const int* __restrict__ esrc,
                                              const float* __restrict__ epsp,
                                              const float* __restrict__ mu,
                                              const float* __restrict__ rs,
                                              const float* __restrict__ gamma,
                                              const float* __restrict__ beta,
                                              float* __restrict__ z) {
  const int lane = threadIdx.x & 31;
  const int n = blockIdx.x * 8 + (threadIdx.x >> 5);
  const int c = lane << 2;
  float4 m, r, g, b;
  if (MODE == 1) {
    m = *(const float4*)(mu + c);
    r = *(const float4*)(rs + c);
    g = *(const float4*)(gamma + c);
    b = *(const float4*)(beta + c);
  }
  const float e = 1.0f + epsp[0];
  const int o0 = off[n], o1 = off[n + 1];

  float4 self = *(const float4*)(h + (long)n * D + c);
  if (MODE == 1) self = bn_relu4(self, m, r, g, b);
  float4 acc = make_float4(e * self.x, e * self.y, e * self.z, e * self.w);

  int j = o0;
  for (; j + 1 < o1; j += 2) {
    int s0 = esrc[j], s1 = esrc[j + 1];
    float4 v0 = *(const float4*)(h + (long)s0 * D + c);
    float4 v1 = *(const float4*)(h + (long)s1 * D + c);
    if (MODE == 1) { v0 = bn_relu4(v0, m, r, g, b); v1 = bn_relu4(v1, m, r, g, b); }
    acc.x += v0.x + v1.x; acc.y += v0.y + v1.y;
    acc.z += v0.z + v1.z; acc.w += v0.w + v1.w;
  }
  if (j < o1) {
    int s0 = esrc[j];
    float4 v0 = *(const float4*)(h + (long)s0 * D + c);
    if (MODE == 1) v0 = bn_relu4(v0, m, r, g, b);
    acc.x += v0.x; acc.y += v0.y; acc.z += v0.z; acc.w += v0.w;
  }
  *(float4*)(z + (long)n * D + c) = acc;
}

// ---------------- GEMM: out[M x 128] = T(in) @ W ----------------
template <int MODE>
__global__ __launch_bounds__(256) void k_gemm(const float* __restrict__ in,
                                              const float* __restrict__ W,
                                              float* __restrict__ out,
                                              const float* __restrict__ mu,
                                              const float* __restrict__ rs,
                                              const float* __restrict__ gamma,
                                              const float* __restrict__ beta) {
  __shared__ float Zs[64][132];
  __shared__ float Ws[32][128];
  const int t = threadIdx.x;
  const int row0 = blockIdx.x * 64;

#pragma unroll
  for (int i = 0; i < 8; i++) {
    int q = t + i * 256;
    int r = q >> 5, c = (q & 31) << 2;
    int grow = row0 + r;
    float4 v = make_float4(0.f, 0.f, 0.f, 0.f);
    if (grow < N_NODES) {
      v = *(const float4*)(in + (long)grow * D + c);
      if (MODE == 1) {
        v.x = fmaxf(fmaf((v.x - mu[c]) * rs[c], gamma[c], beta[c]), 0.f);
        v.y = fmaxf(fmaf((v.y - mu[c + 1]) * rs[c + 1], gamma[c + 1], beta[c + 1]), 0.f);
        v.z = fmaxf(fmaf((v.z - mu[c + 2]) * rs[c + 2], gamma[c + 2], beta[c + 2]), 0.f);
        v.w = fmaxf(fmaf((v.w - mu[c + 3]) * rs[c + 3], gamma[c + 3], beta[c + 3]), 0.f);
      }
    }
    *(float4*)&Zs[r][c] = v;
  }

  float acc[4][8];
#pragma unroll
  for (int r = 0; r < 4; r++)
#pragma unroll
    for (int c = 0; c < 8; c++) acc[r][c] = 0.f;

  const int rg = (t >> 4) << 2;
  const int cg = (t & 15) << 3;

  for (int kc = 0; kc < D; kc += 32) {
#pragma unroll
    for (int i = 0; i < 4; i++) {
      int q = t + i * 256;
      int kr = q >> 5, c = (q & 31) << 2;
      *(float4*)&Ws[kr][c] = *(const float4*)(W + (long)(kc + kr) * D + c);
    }
    __syncthreads();
#pragma unroll
    for (int k = 0; k < 32; k++) {
      float a0 = Zs[rg + 0][kc + k];
      float a1 = Zs[rg + 1][kc + k];
      float a2 = Zs[rg + 2][kc + k];
      float a3 = Zs[rg + 3][kc + k];
      float4 b0 = *(float4*)&Ws[k][cg];
      float4 b1 = *(float4*)&Ws[k][cg + 4];
      acc[0][0] = fmaf(a0, b0.x, acc[0][0]); acc[0][1] = fmaf(a0, b0.y, acc[0][1]);
      acc[0][2] = fmaf(a0, b0.z, acc[0][2]); acc[0][3] = fmaf(a0, b0.w, acc[0][3]);
      acc[0][4] = fmaf(a0, b1.x, acc[0][4]); acc[0][5] = fmaf(a0, b1.y, acc[0][5]);
      acc[0][6] = fmaf(a0, b1.z, acc[0][6]); acc[0][7] = fmaf(a0, b1.w, acc[0][7]);
      acc[1][0] = fmaf(a1, b0.x, acc[1][0]); acc[1][1] = fmaf(a1, b0.y, acc[1][1]);
      acc[1][2] = fmaf(a1, b0.z, acc[1][2]); acc[1][3] = fmaf(a1, b0.w, acc[1][3]);
      acc[1][4] = fmaf(a1, b1.x, acc[1][4]); acc[1][5] = fmaf(a1, b1.y, acc[1][5]);
      acc[1][6] = fmaf(a1, b1.z, acc[1][6]); acc[1][7] = fmaf(a1, b1.w, acc[1][7]);
      acc[2][0] = fmaf(a2, b0.x, acc[2][0]); acc[2][1] = fmaf(a2, b0.y, acc[2][1]);
      acc[2][2] = fmaf(a2, b0.z, acc[2][2]); acc[2][3] = fmaf(a2, b0.w, acc[2][3]);
      acc[2][4] = fmaf(a2, b1.x, acc[2][4]); acc[2][5] = fmaf(a2, b1.y, acc[2][5]);
      acc[2][6] = fmaf(a2, b1.z, acc[2][6]); acc[2][7] = fmaf(a2, b1.w, acc[2][7]);
      acc[3][0] = fmaf(a3, b0.x, acc[3][0]); acc[3][1] = fmaf(a3, b0.y, acc[3][1]);
      acc[3][2] = fmaf(a3, b0.z, acc[3][2]); acc[3][3] = fmaf(a3, b0.w, acc[3][3]);
      acc[3][4] = fmaf(a3, b1.x, acc[3][4]); acc[3][5] = fmaf(a3, b1.y, acc[3][5]);
      acc[3][6] = fmaf(a3, b1.z, acc[3][6]); acc[3][7] = fmaf(a3, b1.w, acc[3][7]);
    }
    __syncthreads();
  }

#pragma unroll
  for (int r = 0; r < 4; r++) {
    int grow = row0 + rg + r;
    if (grow < N_NODES) {
      float4 o0 = make_float4(acc[r][0], acc[r][1], acc[r][2], acc[r][3]);
      float4 o1 = make_float4(acc[r][4], acc[r][5], acc[r][6], acc[r][7]);
      *(float4*)(out + (long)grow * D + cg) = o0;
      *(float4*)(out + (long)grow * D + cg + 4) = o1;
    }
  }
}

// ---------------- BN column stats ----------------
__global__ __launch_bounds__(256) void k_stats(const float* __restrict__ y,
                                               float* __restrict__ ssum,
                                               float* __restrict__ ssq) {
  int f = threadIdx.x & 127;
  int rr = threadIdx.x >> 7;
  float s = 0.f, q = 0.f;
  for (int row = blockIdx.x * 2 + rr; row < N_NODES; row += gridDim.x * 2) {
    float v = y[(long)row * D + f];
    s += v;
    q = fmaf(v, v, q);
  }
  __shared__ float Ls[256], Lq[256];
  Ls[threadIdx.x] = s; Lq[threadIdx.x] = q;
  __syncthreads();
  if (rr == 0) {
    s += Ls[threadIdx.x + 128];
    q += Lq[threadIdx.x + 128];
    atomicAdd(&ssum[f], s);
    atomicAdd(&ssq[f], q);
  }
}

__global__ void k_bnfin(const float* __restrict__ ssum, const float* __restrict__ ssq,
                        float* __restrict__ mu, float* __restrict__ rs) {
  int f = threadIdx.x;
  float m = ssum[f] * (1.0f / (float)N_NODES);
  float v = ssq[f] * (1.0f / (float)N_NODES) - m * m;
  mu[f] = m;
  rs[f] = rsqrtf(v + BN_EPS);
}

// ---------------- final BN2 + ReLU (last layer only) ----------------
__global__ void k_ew(const float* __restrict__ y, const float* __restrict__ mu,
                     const float* __restrict__ rs, const float* __restrict__ gamma,
                     const float* __restrict__ beta, float* __restrict__ out) {
  long i = (long)(blockIdx.x * blockDim.x + threadIdx.x) * 4;
  if (i >= (long)N_NODES * D) return;
  int c = (int)(i & 127);
  float4 v = *(const float4*)(y + i);
  v.x = fmaxf(fmaf((v.x - mu[c]) * rs[c], gamma[c], beta[c]), 0.f);
  v.y = fmaxf(fmaf((v.y - mu[c + 1]) * rs[c + 1], gamma[c + 1], beta[c + 1]), 0.f);
  v.z = fmaxf(fmaf((v.z - mu[c + 2]) * rs[c + 2], gamma[c + 2], beta[c + 2]), 0.f);
  v.w = fmaxf(fmaf((v.w - mu[c + 3]) * rs[c + 3], gamma[c + 3], beta[c + 3]), 0.f);
  *(float4*)(out + i) = v;
}

// ---------------- graph readout ----------------
#define RCH 512
__global__ __launch_bounds__(128) void k_readout(const float* __restrict__ h,
                                                 const int* __restrict__ batch,
                                                 float* __restrict__ gsum,
                                                 int* __restrict__ gcnt) {
  int start = blockIdx.x * RCH;
  int end = min(start + RCH, N_NODES);
  if (start >= end) return;
  int f = threadIdx.x;
  float acc = 0.f;
  int cnt = 0;
  int curg = batch[start];
  for (int n = start; n < end; n++) {
    int g = batch[n];
    if (g != curg) {
      atomicAdd(&gsum[curg * D + f], acc);
      if (f == 0) atomicAdd(&gcnt[curg], cnt);
      acc = 0.f; cnt = 0; curg = g;
    }
    acc += h[(long)n * D + f];
    cnt++;
  }
  atomicAdd(&gsum[curg * D + f], acc);
  if (f == 0) atomicAdd(&gcnt[curg], cnt);
}

__global__ __launch_bounds__(128) void k_gnorm(const float* __restrict__ gsum,
                                               const int* __restrict__ gcnt,
                                               float* __restrict__ out) {
  __shared__ float red[128];
  int g = blockIdx.x, f = threadIdx.x;
  float c = (float)gcnt[g];
  float v = gsum[g * D + f] / fmaxf(c, 1.0f);
  red[f] = v * v;
  __syncthreads();
  for (int o = 64; o > 0; o >>= 1) {
    if (f < o) red[f] += red[f + o];
    __syncthreads();
  }
  float nrm = sqrtf(red[0]);
  out[(long)g * D + f] = v / fmaxf(nrm, 1e-12f);
}

extern "C" void kernel_launch(void* const* d_in, const int* in_sizes, int n_in,
                              void* d_out, int out_size, void* d_ws, size_t ws_size,
                              hipStream_t stream) {
  const float* x   = (const float*)d_in[0];
  const int*   ei  = (const int*)d_in[1];
  const int*   bat = (const int*)d_in[2];
  const float* W1  = (const float*)d_in[3];
  const float* g1  = (const float*)d_in[4];
  const float* b1  = (const float*)d_in[5];
  const float* W2  = (const float*)d_in[6];
  const float* g2  = (const float*)d_in[7];
  const float* b2  = (const float*)d_in[8];
  const float* eps = (const float*)d_in[9];
  float* out = (float*)d_out;

  char* w = (char*)d_ws;
  float* bufA = (float*)w; w += (size_t)N_NODES * D * 4;
  float* bufB = (float*)w; w += (size_t)N_NODES * D * 4;
  float* bufC = (float*)w; w += (size_t)N_NODES * D * 4;
  int* deg  = (int*)w; w += 400016;
  int* off  = (int*)w; w += 400016;
  int* cur  = (int*)w; w += 400016;
  int* esrc = (int*)w; w += (size_t)N_EDGES * 4;
  int* bsum = (int*)w; w += 1024;
  int* bpre = (int*)w; w += 1024;
  float* ssum = (float*)w; w += 512;
  float* ssq  = (float*)w; w += 512;
  float* mu1  = (float*)w; w += 512;
  float* rs1  = (float*)w; w += 512;
  float* mu2  = (float*)w; w += 512;
  float* rs2  = (float*)w; w += 512;
  float* gsum = (float*)w; w += (size_t)N_GRAPHS * D * 4;
  int* gcnt   = (int*)w; w += 256;

  // build CSR once (edge_index is layer-invariant)
  hipMemsetAsync(deg, 0, (size_t)N_NODES * 4, stream);
  k_hist<<<(N_EDGES + 255) / 256, 256, 0, stream>>>(ei + N_EDGES, deg);
  k_scan1<<<SCAN_NB, 256, 0, stream>>>(deg, bsum);
  k_scan2<<<1, 256, 0, stream>>>(bsum, bpre);
  k_scan3<<<SCAN_NB, 256, 0, stream>>>(deg, bpre, off, cur);
  k_place<<<(N_EDGES + 255) / 256, 256, 0, stream>>>(ei, cur, esrc);

  const int gemm_grid = (N_NODES + 63) / 64;
  const int aggz_grid = N_NODES / 8;  // 12500 exactly

  // Buffers: z in bufA, y1 in bufB, y2 in bufC every layer.
  // Next layer's aggz reads bufC (pre-BN y2) with on-the-fly BN2+ReLU.
  for (int l = 0; l < 3; l++) {
    if (l == 0) {
      k_aggz<0><<<aggz_grid, 256, 0, stream>>>(x, off, esrc, eps + l,
                                               nullptr, nullptr, nullptr, nullptr, bufA);
    } else {
      k_aggz<1><<<aggz_grid, 256, 0, stream>>>(bufC, off, esrc, eps + l,
                                               mu2, rs2, g2 + (size_t)(l - 1) * D,
                                               b2 + (size_t)(l - 1) * D, bufA);
    }
    k_gemm<0><<<gemm_grid, 256, 0, stream>>>(bufA, W1 + (size_t)l * D * D, bufB,
                                             nullptr, nullptr, nullptr, nullptr);
    hipMemsetAsync(ssum, 0, 1024, stream);  // ssum+ssq contiguous
    k_stats<<<512, 256, 0, stream>>>(bufB, ssum, ssq);
    k_bnfin<<<1, 128, 0, stream>>>(ssum, ssq, mu1, rs1);
    k_gemm<1><<<gemm_grid, 256, 0, stream>>>(bufB, W2 + (size_t)l * D * D, bufC,
                                             mu1, rs1, g1 + (size_t)l * D, b1 + (size_t)l * D);
    hipMemsetAsync(ssum, 0, 1024, stream);
    k_stats<<<512, 256, 0, stream>>>(bufC, ssum, ssq);
    k_bnfin<<<1, 128, 0, stream>>>(ssum, ssq, mu2, rs2);
  }
  // node_emb = relu(bn2(y2 of layer 2))
  k_ew<<<(N_NODES * D / 4 + 255) / 256, 256, 0, stream>>>(bufC, mu2, rs2,
                                                          g2 + 2 * D, b2 + 2 * D, out);

  hipMemsetAsync(gsum, 0, (size_t)N_GRAPHS * D * 4, stream);
  hipMemsetAsync(gcnt, 0, (size_t)N_GRAPHS * 4, stream);
  k_readout<<<(N_NODES + RCH - 1) / RCH, 128, 0, stream>>>(out, bat, gsum, gcnt);
  k_gnorm<<<N_GRAPHS, 128, 0, stream>>>(gsum, gcnt, out + (size_t)N_NODES * D);
}

// Round 3
// 1074.578 us; speedup vs baseline: 1.7123x; 1.3277x over previous
//
#include <hip/hip_runtime.h>

#define N_NODES 100000
#define N_EDGES 1600000
#define D 128
#define N_GRAPHS 64
#define BN_EPS 1e-5f
#define NSLICE 16

// ---------------- CSR build (dst-keyed) ----------------
__global__ void k_hist(const int* __restrict__ dst, int* __restrict__ deg) {
  int i = blockIdx.x * blockDim.x + threadIdx.x;
  if (i < N_EDGES) atomicAdd(&deg[dst[i]], 1);
}

#define SCAN_CH 512
#define SCAN_NB ((N_NODES + SCAN_CH - 1) / SCAN_CH)  // 196

__global__ __launch_bounds__(256) void k_scan1(const int* __restrict__ deg,
                                               int* __restrict__ bsum) {
  __shared__ int ls[256];
  int base = blockIdx.x * SCAN_CH;
  int t = threadIdx.x;
  int s = 0;
  for (int i = t; i < SCAN_CH; i += 256) {
    int idx = base + i;
    if (idx < N_NODES) s += deg[idx];
  }
  ls[t] = s;
  __syncthreads();
  for (int o = 128; o > 0; o >>= 1) {
    if (t < o) ls[t] += ls[t + o];
    __syncthreads();
  }
  if (t == 0) bsum[blockIdx.x] = ls[0];
}

__global__ __launch_bounds__(256) void k_scan2(const int* __restrict__ bsum,
                                               int* __restrict__ bpre) {
  __shared__ int ls[256];
  int t = threadIdx.x;
  int v = (t < SCAN_NB) ? bsum[t] : 0;
  ls[t] = v;
  __syncthreads();
  for (int o = 1; o < 256; o <<= 1) {
    int u = (t >= o) ? ls[t - o] : 0;
    __syncthreads();
    ls[t] += u;
    __syncthreads();
  }
  if (t < SCAN_NB) bpre[t] = ls[t] - v;  // exclusive
}

__global__ __launch_bounds__(256) void k_scan3(const int* __restrict__ deg,
                                               const int* __restrict__ bpre,
                                               int* __restrict__ off,
                                               int* __restrict__ cur) {
  __shared__ int ls[256];
  int base = blockIdx.x * SCAN_CH;
  int t = threadIdx.x;
  int i0 = base + t * 2;
  int d0 = (i0 < N_NODES) ? deg[i0] : 0;
  int d1 = (i0 + 1 < N_NODES) ? deg[i0 + 1] : 0;
  int s = d0 + d1;
  ls[t] = s;
  __syncthreads();
  for (int o = 1; o < 256; o <<= 1) {
    int u = (t >= o) ? ls[t - o] : 0;
    __syncthreads();
    ls[t] += u;
    __syncthreads();
  }
  int pre = bpre[blockIdx.x] + ls[t] - s;
  if (i0 < N_NODES) { off[i0] = pre; cur[i0] = pre; }
  if (i0 + 1 < N_NODES) { off[i0 + 1] = pre + d0; cur[i0 + 1] = pre + d0; }
  if (blockIdx.x == 0 && t == 0) off[N_NODES] = N_EDGES;
}

__global__ void k_place(const int* __restrict__ ei, int* __restrict__ cur,
                        int* __restrict__ esrc) {
  int i = blockIdx.x * blockDim.x + threadIdx.x;
  if (i < N_EDGES) {
    int s = ei[i];
    int d = ei[N_EDGES + i];
    int p = atomicAdd(&cur[d], 1);
    esrc[p] = s;
  }
}

// ---------------- agg + (1+eps)*h, optional BN+ReLU on gathered rows --------
__device__ inline float4 bn_relu4(float4 v, float4 m, float4 r, float4 g, float4 b) {
  v.x = fmaxf(fmaf((v.x - m.x) * r.x, g.x, b.x), 0.f);
  v.y = fmaxf(fmaf((v.y - m.y) * r.y, g.y, b.y), 0.f);
  v.z = fmaxf(fmaf((v.z - m.z) * r.z, g.z, b.z), 0.f);
  v.w = fmaxf(fmaf((v.w - m.w) * r.w, g.w, b.w), 0.f);
  return v;
}

template <int MODE>
__global__ __launch_bounds__(256) void k_aggz(const float* __restrict__ h,
                                              const int* __restrict__ off,
                                              const int* __restrict__ esrc,
                                              const float* __restrict__ epsp,
                                              const float* __restrict__ mu,
                                              const float* __restrict__ rs,
                                              const float* __restrict__ gamma,
                                              const float* __restrict__ beta,
                                              float* __restrict__ z) {
  const int lane = threadIdx.x & 31;
  const int n = blockIdx.x * 8 + (threadIdx.x >> 5);
  const int c = lane << 2;
  float4 m, r, g, b;
  if (MODE == 1) {
    m = *(const float4*)(mu + c);
    r = *(const float4*)(rs + c);
    g = *(const float4*)(gamma + c);
    b = *(const float4*)(beta + c);
  }
  const float e = 1.0f + epsp[0];
  const int o0 = off[n], o1 = off[n + 1];

  float4 self = *(const float4*)(h + (long)n * D + c);
  if (MODE == 1) self = bn_relu4(self, m, r, g, b);
  float4 acc = make_float4(e * self.x, e * self.y, e * self.z, e * self.w);

  int j = o0;
  for (; j + 1 < o1; j += 2) {
    int s0 = esrc[j], s1 = esrc[j + 1];
    float4 v0 = *(const float4*)(h + (long)s0 * D + c);
    float4 v1 = *(const float4*)(h + (long)s1 * D + c);
    if (MODE == 1) { v0 = bn_relu4(v0, m, r, g, b); v1 = bn_relu4(v1, m, r, g, b); }
    acc.x += v0.x + v1.x; acc.y += v0.y + v1.y;
    acc.z += v0.z + v1.z; acc.w += v0.w + v1.w;
  }
  if (j < o1) {
    int s0 = esrc[j];
    float4 v0 = *(const float4*)(h + (long)s0 * D + c);
    if (MODE == 1) v0 = bn_relu4(v0, m, r, g, b);
    acc.x += v0.x; acc.y += v0.y; acc.z += v0.z; acc.w += v0.w;
  }
  *(float4*)(z + (long)n * D + c) = acc;
}

// ---------------- GEMM + fused BN column stats ----------------
// out = T(in) @ W; also atomically accumulates per-column sum / sumsq of out
// into ssum/ssq (NSLICE slices to limit same-address contention).
template <int MODE>
__global__ __launch_bounds__(256) void k_gemm(const float* __restrict__ in,
                                              const float* __restrict__ W,
                                              float* __restrict__ out,
                                              const float* __restrict__ mu,
                                              const float* __restrict__ rs,
                                              const float* __restrict__ gamma,
                                              const float* __restrict__ beta,
                                              float* __restrict__ ssum,
                                              float* __restrict__ ssq) {
  __shared__ float smem[64 * 132 + 32 * 128];
  float (*Zs)[132] = (float (*)[132])smem;
  float (*Ws)[128] = (float (*)[128])(smem + 64 * 132);
  const int t = threadIdx.x;
  const int row0 = blockIdx.x * 64;

#pragma unroll
  for (int i = 0; i < 8; i++) {
    int q = t + i * 256;
    int r = q >> 5, c = (q & 31) << 2;
    int grow = row0 + r;
    float4 v = make_float4(0.f, 0.f, 0.f, 0.f);
    if (grow < N_NODES) {
      v = *(const float4*)(in + (long)grow * D + c);
      if (MODE == 1) {
        v.x = fmaxf(fmaf((v.x - mu[c]) * rs[c], gamma[c], beta[c]), 0.f);
        v.y = fmaxf(fmaf((v.y - mu[c + 1]) * rs[c + 1], gamma[c + 1], beta[c + 1]), 0.f);
        v.z = fmaxf(fmaf((v.z - mu[c + 2]) * rs[c + 2], gamma[c + 2], beta[c + 2]), 0.f);
        v.w = fmaxf(fmaf((v.w - mu[c + 3]) * rs[c + 3], gamma[c + 3], beta[c + 3]), 0.f);
      }
    }
    *(float4*)&Zs[r][c] = v;
  }

  float acc[4][8];
#pragma unroll
  for (int r = 0; r < 4; r++)
#pragma unroll
    for (int c = 0; c < 8; c++) acc[r][c] = 0.f;

  const int rg = (t >> 4) << 2;
  const int cg = (t & 15) << 3;

  for (int kc = 0; kc < D; kc += 32) {
#pragma unroll
    for (int i = 0; i < 4; i++) {
      int q = t + i * 256;
      int kr = q >> 5, c = (q & 31) << 2;
      *(float4*)&Ws[kr][c] = *(const float4*)(W + (long)(kc + kr) * D + c);
    }
    __syncthreads();
#pragma unroll
    for (int k = 0; k < 32; k++) {
      float a0 = Zs[rg + 0][kc + k];
      float a1 = Zs[rg + 1][kc + k];
      float a2 = Zs[rg + 2][kc + k];
      float a3 = Zs[rg + 3][kc + k];
      float4 b0 = *(float4*)&Ws[k][cg];
      float4 b1 = *(float4*)&Ws[k][cg + 4];
      acc[0][0] = fmaf(a0, b0.x, acc[0][0]); acc[0][1] = fmaf(a0, b0.y, acc[0][1]);
      acc[0][2] = fmaf(a0, b0.z, acc[0][2]); acc[0][3] = fmaf(a0, b0.w, acc[0][3]);
      acc[0][4] = fmaf(a0, b1.x, acc[0][4]); acc[0][5] = fmaf(a0, b1.y, acc[0][5]);
      acc[0][6] = fmaf(a0, b1.z, acc[0][6]); acc[0][7] = fmaf(a0, b1.w, acc[0][7]);
      acc[1][0] = fmaf(a1, b0.x, acc[1][0]); acc[1][1] = fmaf(a1, b0.y, acc[1][1]);
      acc[1][2] = fmaf(a1, b0.z, acc[1][2]); acc[1][3] = fmaf(a1, b0.w, acc[1][3]);
      acc[1][4] = fmaf(a1, b1.x, acc[1][4]); acc[1][5] = fmaf(a1, b1.y, acc[1][5]);
      acc[1][6] = fmaf(a1, b1.z, acc[1][6]); acc[1][7] = fmaf(a1, b1.w, acc[1][7]);
      acc[2][0] = fmaf(a2, b0.x, acc[2][0]); acc[2][1] = fmaf(a2, b0.y, acc[2][1]);
      acc[2][2] = fmaf(a2, b0.z, acc[2][2]); acc[2][3] = fmaf(a2, b0.w, acc[2][3]);
      acc[2][4] = fmaf(a2, b1.x, acc[2][4]); acc[2][5] = fmaf(a2, b1.y, acc[2][5]);
      acc[2][6] = fmaf(a2, b1.z, acc[2][6]); acc[2][7] = fmaf(a2, b1.w, acc[2][7]);
      acc[3][0] = fmaf(a3, b0.x, acc[3][0]); acc[3][1] = fmaf(a3, b0.y, acc[3][1]);
      acc[3][2] = fmaf(a3, b0.z, acc[3][2]); acc[3][3] = fmaf(a3, b0.w, acc[3][3]);
      acc[3][4] = fmaf(a3, b1.x, acc[3][4]); acc[3][5] = fmaf(a3, b1.y, acc[3][5]);
      acc[3][6] = fmaf(a3, b1.z, acc[3][6]); acc[3][7] = fmaf(a3, b1.w, acc[3][7]);
    }
    __syncthreads();
  }

  // ---- store output tile ----
#pragma unroll
  for (int r = 0; r < 4; r++) {
    int grow = row0 + rg + r;
    if (grow < N_NODES) {
      float4 o0 = make_float4(acc[r][0], acc[r][1], acc[r][2], acc[r][3]);
      float4 o1 = make_float4(acc[r][4], acc[r][5], acc[r][6], acc[r][7]);
      *(float4*)(out + (long)grow * D + cg) = o0;
      *(float4*)(out + (long)grow * D + cg + 4) = o1;
    }
  }

  // ---- fused column stats (rows beyond N_NODES contribute exact zeros) ----
  // per-thread partial over its 4 rows, for its 8 columns
  float* psum = smem;         // [16][128] (aliases Zs region; safe after last sync)
  float* psq  = smem + 2048;  // [16][128]
  const int rgid = t >> 4;
#pragma unroll
  for (int j = 0; j < 8; j++) {
    float s = acc[0][j] + acc[1][j] + acc[2][j] + acc[3][j];
    float q = acc[0][j] * acc[0][j] + acc[1][j] * acc[1][j] +
              acc[2][j] * acc[2][j] + acc[3][j] * acc[3][j];
    psum[rgid * 128 + cg + j] = s;
    psq[rgid * 128 + cg + j] = q;
  }
  __syncthreads();
  if (t < 128) {
    float S = 0.f, Q = 0.f;
#pragma unroll
    for (int i = 0; i < 16; i++) {
      S += psum[i * 128 + t];
      Q += psq[i * 128 + t];
    }
    int slice = blockIdx.x & (NSLICE - 1);
    atomicAdd(&ssum[slice * 128 + t], S);
    atomicAdd(&ssq[slice * 128 + t], Q);
  }
}

__global__ void k_bnfin(const float* __restrict__ ssum, const float* __restrict__ ssq,
                        float* __restrict__ mu, float* __restrict__ rs) {
  int f = threadIdx.x;
  float S = 0.f, Q = 0.f;
  for (int i = 0; i < NSLICE; i++) { S += ssum[i * 128 + f]; Q += ssq[i * 128 + f]; }
  float m = S * (1.0f / (float)N_NODES);
  float v = Q * (1.0f / (float)N_NODES) - m * m;
  mu[f] = m;
  rs[f] = rsqrtf(v + BN_EPS);
}

// ---------------- fused BN2+ReLU + node_emb write + graph readout ------------
#define RCH 64
__global__ __launch_bounds__(128) void k_readout(const float* __restrict__ y,
                                                 const int* __restrict__ batch,
                                                 const float* __restrict__ mu,
                                                 const float* __restrict__ rs,
                                                 const float* __restrict__ gamma,
                                                 const float* __restrict__ beta,
                                                 float* __restrict__ node_out,
                                                 float* __restrict__ gsum,
                                                 int* __restrict__ gcnt) {
  int start = blockIdx.x * RCH;
  int end = min(start + RCH, N_NODES);
  if (start >= end) return;
  int f = threadIdx.x;
  float m = mu[f], r = rs[f], g = gamma[f], b = beta[f];
  float acc = 0.f;
  int cnt = 0;
  int curg = batch[start];
  for (int n = start; n < end; n++) {
    int gg = batch[n];
    float v = fmaxf(fmaf((y[(long)n * D + f] - m) * r, g, b), 0.f);
    node_out[(long)n * D + f] = v;
    if (gg != curg) {
      atomicAdd(&gsum[curg * D + f], acc);
      if (f == 0) atomicAdd(&gcnt[curg], cnt);
      acc = 0.f; cnt = 0; curg = gg;
    }
    acc += v;
    cnt++;
  }
  atomicAdd(&gsum[curg * D + f], acc);
  if (f == 0) atomicAdd(&gcnt[curg], cnt);
}

__global__ __launch_bounds__(128) void k_gnorm(const float* __restrict__ gsum,
                                               const int* __restrict__ gcnt,
                                               float* __restrict__ out) {
  __shared__ float red[128];
  int g = blockIdx.x, f = threadIdx.x;
  float c = (float)gcnt[g];
  float v = gsum[g * D + f] / fmaxf(c, 1.0f);
  red[f] = v * v;
  __syncthreads();
  for (int o = 64; o > 0; o >>= 1) {
    if (f < o) red[f] += red[f + o];
    __syncthreads();
  }
  float nrm = sqrtf(red[0]);
  out[(long)g * D + f] = v / fmaxf(nrm, 1e-12f);
}

extern "C" void kernel_launch(void* const* d_in, const int* in_sizes, int n_in,
                              void* d_out, int out_size, void* d_ws, size_t ws_size,
                              hipStream_t stream) {
  const float* x   = (const float*)d_in[0];
  const int*   ei  = (const int*)d_in[1];
  const int*   bat = (const int*)d_in[2];
  const float* W1  = (const float*)d_in[3];
  const float* g1  = (const float*)d_in[4];
  const float* b1  = (const float*)d_in[5];
  const float* W2  = (const float*)d_in[6];
  const float* g2  = (const float*)d_in[7];
  const float* b2  = (const float*)d_in[8];
  const float* eps = (const float*)d_in[9];
  float* out = (float*)d_out;

  char* w = (char*)d_ws;
  float* bufA = (float*)w; w += (size_t)N_NODES * D * 4;
  float* bufB = (float*)w; w += (size_t)N_NODES * D * 4;
  float* bufC = (float*)w; w += (size_t)N_NODES * D * 4;
  int* deg  = (int*)w; w += 400016;
  int* off  = (int*)w; w += 400016;
  int* cur  = (int*)w; w += 400016;
  int* esrc = (int*)w; w += (size_t)N_EDGES * 4;
  int* bsum = (int*)w; w += 1024;
  int* bpre = (int*)w; w += 1024;
  // 6 stat sets (2 per layer), each NSLICE*128 sum + NSLICE*128 sq
  float* stats = (float*)w; w += (size_t)6 * 2 * NSLICE * 128 * 4;  // 96 KB
  float* mu1  = (float*)w; w += 512;
  float* rs1  = (float*)w; w += 512;
  float* mu2  = (float*)w; w += 512;
  float* rs2  = (float*)w; w += 512;
  float* gsum = (float*)w; w += (size_t)N_GRAPHS * D * 4;
  int* gcnt   = (int*)w; w += 256;

  // build CSR once (edge_index is layer-invariant)
  hipMemsetAsync(deg, 0, (size_t)N_NODES * 4, stream);
  hipMemsetAsync(stats, 0, (size_t)6 * 2 * NSLICE * 128 * 4, stream);
  hipMemsetAsync(gsum, 0, (size_t)N_GRAPHS * D * 4 + 256, stream);  // gsum+gcnt contiguous
  k_hist<<<(N_EDGES + 255) / 256, 256, 0, stream>>>(ei + N_EDGES, deg);
  k_scan1<<<SCAN_NB, 256, 0, stream>>>(deg, bsum);
  k_scan2<<<1, 256, 0, stream>>>(bsum, bpre);
  k_scan3<<<SCAN_NB, 256, 0, stream>>>(deg, bpre, off, cur);
  k_place<<<(N_EDGES + 255) / 256, 256, 0, stream>>>(ei, cur, esrc);

  const int gemm_grid = (N_NODES + 63) / 64;
  const int aggz_grid = N_NODES / 8;  // 12500 exactly

  for (int l = 0; l < 3; l++) {
    float* s1 = stats + (size_t)(l * 2 + 0) * 2 * NSLICE * 128;
    float* q1 = s1 + NSLICE * 128;
    float* s2 = stats + (size_t)(l * 2 + 1) * 2 * NSLICE * 128;
    float* q2 = s2 + NSLICE * 128;
    if (l == 0) {
      k_aggz<0><<<aggz_grid, 256, 0, stream>>>(x, off, esrc, eps + l,
                                               nullptr, nullptr, nullptr, nullptr, bufA);
    } else {
      k_aggz<1><<<aggz_grid, 256, 0, stream>>>(bufC, off, esrc, eps + l,
                                               mu2, rs2, g2 + (size_t)(l - 1) * D,
                                               b2 + (size_t)(l - 1) * D, bufA);
    }
    k_gemm<0><<<gemm_grid, 256, 0, stream>>>(bufA, W1 + (size_t)l * D * D, bufB,
                                             nullptr, nullptr, nullptr, nullptr, s1, q1);
    k_bnfin<<<1, 128, 0, stream>>>(s1, q1, mu1, rs1);
    k_gemm<1><<<gemm_grid, 256, 0, stream>>>(bufB, W2 + (size_t)l * D * D, bufC,
                                             mu1, rs1, g1 + (size_t)l * D, b1 + (size_t)l * D,
                                             s2, q2);
    k_bnfin<<<1, 128, 0, stream>>>(s2, q2, mu2, rs2);
  }

  // fused: node_emb = relu(bn2(y2)), graph sums, counts
  k_readout<<<(N_NODES + RCH - 1) / RCH, 128, 0, stream>>>(bufC, bat, mu2, rs2,
                                                           g2 + 2 * D, b2 + 2 * D,
                                                           out, gsum, gcnt);
  k_gnorm<<<N_GRAPHS, 128, 0, stream>>>(gsum, gcnt, out + (size_t)N_NODES * D);
}

// Round 4
// 775.108 us; speedup vs baseline: 2.3738x; 1.3864x over previous
//
#include <hip/hip_runtime.h>

#define N_NODES 100000
#define N_EDGES 1600000
#define D 128
#define N_GRAPHS 64
#define BN_EPS 1e-5f
#define NSLICE 16

typedef short short8 __attribute__((ext_vector_type(8)));
typedef float f32x4 __attribute__((ext_vector_type(4)));

__device__ inline unsigned short f2bf(float f) {
  unsigned int u = __float_as_uint(f);
  u += 0x7fffu + ((u >> 16) & 1);
  return (unsigned short)(u >> 16);
}
__device__ inline float bf2f(unsigned short h) {
  return __uint_as_float(((unsigned int)h) << 16);
}
__device__ inline void unpack8(uint4 u, float* f) {
  f[0] = __uint_as_float(u.x << 16); f[1] = __uint_as_float(u.x & 0xffff0000u);
  f[2] = __uint_as_float(u.y << 16); f[3] = __uint_as_float(u.y & 0xffff0000u);
  f[4] = __uint_as_float(u.z << 16); f[5] = __uint_as_float(u.z & 0xffff0000u);
  f[6] = __uint_as_float(u.w << 16); f[7] = __uint_as_float(u.w & 0xffff0000u);
}
__device__ inline uint4 pack8(const float* f) {
  uint4 u;
  u.x = f2bf(f[0]) | ((unsigned)f2bf(f[1]) << 16);
  u.y = f2bf(f[2]) | ((unsigned)f2bf(f[3]) << 16);
  u.z = f2bf(f[4]) | ((unsigned)f2bf(f[5]) << 16);
  u.w = f2bf(f[6]) | ((unsigned)f2bf(f[7]) << 16);
  return u;
}

// ---------------- input casts / weight prep ----------------
__global__ __launch_bounds__(256) void k_cast(const float* __restrict__ in,
                                              unsigned short* __restrict__ o) {
  long i = ((long)blockIdx.x * blockDim.x + threadIdx.x) * 8;
  if (i >= (long)N_NODES * D) return;
  float4 a = *(const float4*)(in + i);
  float4 b = *(const float4*)(in + i + 4);
  float f[8] = {a.x, a.y, a.z, a.w, b.x, b.y, b.z, b.w};
  *(uint4*)(o + i) = pack8(f);
}

// Wt[mat][n][k] = bf16(W[mat][k][n]); mat = layer*2 + (0:W1,1:W2)
__global__ __launch_bounds__(128) void k_wprep(const float* __restrict__ W1,
                                               const float* __restrict__ W2,
                                               unsigned short* __restrict__ Wt) {
  int m = blockIdx.x;   // 0..5
  int n = blockIdx.y;   // 0..127
  int k = threadIdx.x;  // 0..127
  int l = m >> 1, s = m & 1;
  const float* W = (s == 0 ? W1 : W2) + (size_t)l * D * D;
  Wt[((size_t)m * D + n) * D + k] = f2bf(W[(size_t)k * D + n]);
}

// ---------------- CSR build (dst-keyed) ----------------
__global__ void k_hist(const int* __restrict__ dst, int* __restrict__ deg) {
  int i = blockIdx.x * blockDim.x + threadIdx.x;
  if (i < N_EDGES) atomicAdd(&deg[dst[i]], 1);
}

#define SCAN_CH 512
#define SCAN_NB ((N_NODES + SCAN_CH - 1) / SCAN_CH)  // 196

__global__ __launch_bounds__(256) void k_scan1(const int* __restrict__ deg,
                                               int* __restrict__ bsum) {
  __shared__ int ls[256];
  int base = blockIdx.x * SCAN_CH;
  int t = threadIdx.x;
  int s = 0;
  for (int i = t; i < SCAN_CH; i += 256) {
    int idx = base + i;
    if (idx < N_NODES) s += deg[idx];
  }
  ls[t] = s;
  __syncthreads();
  for (int o = 128; o > 0; o >>= 1) {
    if (t < o) ls[t] += ls[t + o];
    __syncthreads();
  }
  if (t == 0) bsum[blockIdx.x] = ls[0];
}

__global__ __launch_bounds__(256) void k_scan2(const int* __restrict__ bsum,
                                               int* __restrict__ bpre) {
  __shared__ int ls[256];
  int t = threadIdx.x;
  int v = (t < SCAN_NB) ? bsum[t] : 0;
  ls[t] = v;
  __syncthreads();
  for (int o = 1; o < 256; o <<= 1) {
    int u = (t >= o) ? ls[t - o] : 0;
    __syncthreads();
    ls[t] += u;
    __syncthreads();
  }
  if (t < SCAN_NB) bpre[t] = ls[t] - v;  // exclusive
}

__global__ __launch_bounds__(256) void k_scan3(const int* __restrict__ deg,
                                               const int* __restrict__ bpre,
                                               int* __restrict__ off,
                                               int* __restrict__ cur) {
  __shared__ int ls[256];
  int base = blockIdx.x * SCAN_CH;
  int t = threadIdx.x;
  int i0 = base + t * 2;
  int d0 = (i0 < N_NODES) ? deg[i0] : 0;
  int d1 = (i0 + 1 < N_NODES) ? deg[i0 + 1] : 0;
  int s = d0 + d1;
  ls[t] = s;
  __syncthreads();
  for (int o = 1; o < 256; o <<= 1) {
    int u = (t >= o) ? ls[t - o] : 0;
    __syncthreads();
    ls[t] += u;
    __syncthreads();
  }
  int pre = bpre[blockIdx.x] + ls[t] - s;
  if (i0 < N_NODES) { off[i0] = pre; cur[i0] = pre; }
  if (i0 + 1 < N_NODES) { off[i0 + 1] = pre + d0; cur[i0 + 1] = pre + d0; }
  if (blockIdx.x == 0 && t == 0) off[N_NODES] = N_EDGES;
}

__global__ void k_place(const int* __restrict__ ei, int* __restrict__ cur,
                        int* __restrict__ esrc) {
  int i = blockIdx.x * blockDim.x + threadIdx.x;
  if (i < N_EDGES) {
    int s = ei[i];
    int d = ei[N_EDGES + i];
    int p = atomicAdd(&cur[d], 1);
    esrc[p] = s;
  }
}

// ---------------- agg + (1+eps)*h, optional BN+ReLU on gathered rows --------
// bf16 in / bf16 out, f32 accumulate. 16 nodes per 256-thread block,
// 16 lanes per node, 8 features (16B) per lane.
template <int MODE>
__global__ __launch_bounds__(256) void k_aggz(const unsigned short* __restrict__ h,
                                              const int* __restrict__ off,
                                              const int* __restrict__ esrc,
                                              const float* __restrict__ epsp,
                                              const float* __restrict__ mu,
                                              const float* __restrict__ rs,
                                              const float* __restrict__ gamma,
                                              const float* __restrict__ beta,
                                              unsigned short* __restrict__ z) {
  const int sub = threadIdx.x & 15;
  const int n = blockIdx.x * 16 + (threadIdx.x >> 4);
  const int c = sub << 3;
  float M[8], R[8], G[8], B[8];
  if (MODE == 1) {
#pragma unroll
    for (int j = 0; j < 8; j++) {
      M[j] = mu[c + j]; R[j] = rs[c + j]; G[j] = gamma[c + j]; B[j] = beta[c + j];
    }
  }
  const float e = 1.0f + epsp[0];
  const int o0 = off[n], o1 = off[n + 1];

  float acc[8];
  {
    uint4 u = *(const uint4*)(h + (size_t)n * D + c);
    float f[8];
    unpack8(u, f);
#pragma unroll
    for (int j = 0; j < 8; j++) {
      if (MODE == 1) f[j] = fmaxf(fmaf((f[j] - M[j]) * R[j], G[j], B[j]), 0.f);
      acc[j] = e * f[j];
    }
  }
  int j = o0;
  for (; j + 1 < o1; j += 2) {
    int s0 = esrc[j], s1 = esrc[j + 1];
    uint4 u0 = *(const uint4*)(h + (size_t)s0 * D + c);
    uint4 u1 = *(const uint4*)(h + (size_t)s1 * D + c);
    float f0[8], f1[8];
    unpack8(u0, f0);
    unpack8(u1, f1);
#pragma unroll
    for (int q = 0; q < 8; q++) {
      if (MODE == 1) {
        f0[q] = fmaxf(fmaf((f0[q] - M[q]) * R[q], G[q], B[q]), 0.f);
        f1[q] = fmaxf(fmaf((f1[q] - M[q]) * R[q], G[q], B[q]), 0.f);
      }
      acc[q] += f0[q] + f1[q];
    }
  }
  if (j < o1) {
    uint4 u0 = *(const uint4*)(h + (size_t)esrc[j] * D + c);
    float f0[8];
    unpack8(u0, f0);
#pragma unroll
    for (int q = 0; q < 8; q++) {
      if (MODE == 1) f0[q] = fmaxf(fmaf((f0[q] - M[q]) * R[q], G[q], B[q]), 0.f);
      acc[q] += f0[q];
    }
  }
  *(uint4*)(z + (size_t)n * D + c) = pack8(acc);
}

// ---------------- MFMA GEMM: out = T(A) @ W, + fused BN column stats --------
// A: [N_NODES][128] bf16 row-major. Wt: [128][128] bf16, Wt[n][k] = W[k][n].
// Block: 64 rows x 128 cols; 4 waves, wave w = rows [w*16, w*16+16).
// MFMA 16x16x32 bf16: A frag [m=lane&15][k=quad*8+j]; B frag [k=quad*8+j][n=lane&15];
// C/D: col=lane&15, row=quad*4+reg (HW-verified mappings).
template <int MODE>
__global__ __launch_bounds__(256) void k_gemm(const unsigned short* __restrict__ A,
                                              const unsigned short* __restrict__ Wt,
                                              unsigned short* __restrict__ out,
                                              const float* __restrict__ mu,
                                              const float* __restrict__ rs,
                                              const float* __restrict__ gamma,
                                              const float* __restrict__ beta,
                                              float* __restrict__ ssum,
                                              float* __restrict__ ssq) {
  __shared__ unsigned short Zs[64 * 136];  // row stride 136 bf16 (272B): 2-way bank alias = free
  __shared__ float psum[16 * 128];
  __shared__ float psq[16 * 128];
  const int t = threadIdx.x;
  const int row0 = blockIdx.x * 64;

  // stage 64x128 bf16 tile with optional BN+ReLU transform
#pragma unroll
  for (int i = 0; i < 4; i++) {
    int q = t + i * 256;
    int r = q >> 4, cb = (q & 15) << 3;
    int grow = row0 + r;
    uint4 u = make_uint4(0u, 0u, 0u, 0u);
    if (grow < N_NODES) {
      u = *(const uint4*)(A + (size_t)grow * D + cb);
      if (MODE == 1) {
        float f[8];
        unpack8(u, f);
#pragma unroll
        for (int jj = 0; jj < 8; jj++)
          f[jj] = fmaxf(fmaf((f[jj] - mu[cb + jj]) * rs[cb + jj], gamma[cb + jj], beta[cb + jj]), 0.f);
        u = pack8(f);
      }
    }
    *(uint4*)&Zs[r * 136 + cb] = u;
  }
  __syncthreads();

  const int lane = t & 63;
  const int wave = t >> 6;
  const int quad = lane >> 4;
  const int lr = lane & 15;
  const int m0 = wave * 16;

  f32x4 acc[8];
#pragma unroll
  for (int i = 0; i < 8; i++) acc[i] = (f32x4){0.f, 0.f, 0.f, 0.f};

#pragma unroll
  for (int kc = 0; kc < 128; kc += 32) {
    short8 af = *(const short8*)&Zs[(m0 + lr) * 136 + kc + quad * 8];
#pragma unroll
    for (int nt = 0; nt < 8; nt++) {
      short8 bf = *(const short8*)(Wt + (size_t)(nt * 16 + lr) * D + kc + quad * 8);
      acc[nt] = __builtin_amdgcn_mfma_f32_16x16x32_bf16(af, bf, acc[nt], 0, 0, 0);
    }
  }

  // per-lane column partials for BN stats (f32, exact zeros for pad rows)
#pragma unroll
  for (int nt = 0; nt < 8; nt++) {
    int col = nt * 16 + lr;
    float s = acc[nt][0] + acc[nt][1] + acc[nt][2] + acc[nt][3];
    float qq = acc[nt][0] * acc[nt][0] + acc[nt][1] * acc[nt][1] +
               acc[nt][2] * acc[nt][2] + acc[nt][3] * acc[nt][3];
    int gi = (wave * 4 + quad) * 128 + col;
    psum[gi] = s;
    psq[gi] = qq;
  }

  // store output tile (bf16, pre-BN)
#pragma unroll
  for (int rr = 0; rr < 4; rr++) {
    int grow = row0 + m0 + quad * 4 + rr;
    if (grow < N_NODES) {
#pragma unroll
      for (int nt = 0; nt < 8; nt++)
        out[(size_t)grow * D + nt * 16 + lr] = f2bf(acc[nt][rr]);
    }
  }

  __syncthreads();
  if (t < 128) {
    float S = 0.f, Q = 0.f;
#pragma unroll
    for (int i = 0; i < 16; i++) {
      S += psum[i * 128 + t];
      Q += psq[i * 128 + t];
    }
    int slice = blockIdx.x & (NSLICE - 1);
    atomicAdd(&ssum[slice * 128 + t], S);
    atomicAdd(&ssq[slice * 128 + t], Q);
  }
}

__global__ void k_bnfin(const float* __restrict__ ssum, const float* __restrict__ ssq,
                        float* __restrict__ mu, float* __restrict__ rs) {
  int f = threadIdx.x;
  float S = 0.f, Q = 0.f;
  for (int i = 0; i < NSLICE; i++) { S += ssum[i * 128 + f]; Q += ssq[i * 128 + f]; }
  float m = S * (1.0f / (float)N_NODES);
  float v = Q * (1.0f / (float)N_NODES) - m * m;
  mu[f] = m;
  rs[f] = rsqrtf(v + BN_EPS);
}

// ---------------- fused BN2+ReLU + node_emb write + graph readout ------------
#define RCH 64
__global__ __launch_bounds__(128) void k_readout(const unsigned short* __restrict__ y,
                                                 const int* __restrict__ batch,
                                                 const float* __restrict__ mu,
                                                 const float* __restrict__ rs,
                                                 const float* __restrict__ gamma,
                                                 const float* __restrict__ beta,
                                                 float* __restrict__ node_out,
                                                 float* __restrict__ gsum,
                                                 int* __restrict__ gcnt) {
  int start = blockIdx.x * RCH;
  int end = min(start + RCH, N_NODES);
  if (start >= end) return;
  int f = threadIdx.x;
  float m = mu[f], r = rs[f], g = gamma[f], b = beta[f];
  float acc = 0.f;
  int cnt = 0;
  int curg = batch[start];
  for (int n = start; n < end; n++) {
    int gg = batch[n];
    float v = fmaxf(fmaf((bf2f(y[(size_t)n * D + f]) - m) * r, g, b), 0.f);
    node_out[(size_t)n * D + f] = v;
    if (gg != curg) {
      atomicAdd(&gsum[curg * D + f], acc);
      if (f == 0) atomicAdd(&gcnt[curg], cnt);
      acc = 0.f; cnt = 0; curg = gg;
    }
    acc += v;
    cnt++;
  }
  atomicAdd(&gsum[curg * D + f], acc);
  if (f == 0) atomicAdd(&gcnt[curg], cnt);
}

__global__ __launch_bounds__(128) void k_gnorm(const float* __restrict__ gsum,
                                               const int* __restrict__ gcnt,
                                               float* __restrict__ out) {
  __shared__ float red[128];
  int g = blockIdx.x, f = threadIdx.x;
  float c = (float)gcnt[g];
  float v = gsum[g * D + f] / fmaxf(c, 1.0f);
  red[f] = v * v;
  __syncthreads();
  for (int o = 64; o > 0; o >>= 1) {
    if (f < o) red[f] += red[f + o];
    __syncthreads();
  }
  float nrm = sqrtf(red[0]);
  out[(size_t)g * D + f] = v / fmaxf(nrm, 1e-12f);
}

extern "C" void kernel_launch(void* const* d_in, const int* in_sizes, int n_in,
                              void* d_out, int out_size, void* d_ws, size_t ws_size,
                              hipStream_t stream) {
  const float* x   = (const float*)d_in[0];
  const int*   ei  = (const int*)d_in[1];
  const int*   bat = (const int*)d_in[2];
  const float* W1  = (const float*)d_in[3];
  const float* g1  = (const float*)d_in[4];
  const float* b1  = (const float*)d_in[5];
  const float* W2  = (const float*)d_in[6];
  const float* g2  = (const float*)d_in[7];
  const float* b2  = (const float*)d_in[8];
  const float* eps = (const float*)d_in[9];
  float* out = (float*)d_out;

  char* w = (char*)d_ws;
  const size_t FEAT_B = (size_t)N_NODES * D * 2;  // bf16 feature matrix bytes
  unsigned short* xb   = (unsigned short*)w; w += FEAT_B;
  unsigned short* bufA = (unsigned short*)w; w += FEAT_B;
  unsigned short* bufB = (unsigned short*)w; w += FEAT_B;
  unsigned short* bufC = (unsigned short*)w; w += FEAT_B;
  unsigned short* WtB  = (unsigned short*)w; w += (size_t)6 * D * D * 2;
  int* deg  = (int*)w; w += 400016;
  int* off  = (int*)w; w += 400016;
  int* cur  = (int*)w; w += 400016;
  int* esrc = (int*)w; w += (size_t)N_EDGES * 4;
  int* bsum = (int*)w; w += 1024;
  int* bpre = (int*)w; w += 1024;
  float* stats = (float*)w; w += (size_t)6 * 2 * NSLICE * 128 * 4;  // 96 KB
  float* mu1  = (float*)w; w += 512;
  float* rs1  = (float*)w; w += 512;
  float* mu2  = (float*)w; w += 512;
  float* rs2  = (float*)w; w += 512;
  float* gsum = (float*)w; w += (size_t)N_GRAPHS * D * 4;
  int* gcnt   = (int*)w; w += 256;

  hipMemsetAsync(deg, 0, (size_t)N_NODES * 4, stream);
  hipMemsetAsync(stats, 0, (size_t)6 * 2 * NSLICE * 128 * 4, stream);
  hipMemsetAsync(gsum, 0, (size_t)N_GRAPHS * D * 4 + 256, stream);  // gsum+gcnt contiguous

  k_cast<<<(N_NODES * D / 8 + 255) / 256, 256, 0, stream>>>(x, xb);
  k_wprep<<<dim3(6, 128), 128, 0, stream>>>(W1, W2, WtB);

  k_hist<<<(N_EDGES + 255) / 256, 256, 0, stream>>>(ei + N_EDGES, deg);
  k_scan1<<<SCAN_NB, 256, 0, stream>>>(deg, bsum);
  k_scan2<<<1, 256, 0, stream>>>(bsum, bpre);
  k_scan3<<<SCAN_NB, 256, 0, stream>>>(deg, bpre, off, cur);
  k_place<<<(N_EDGES + 255) / 256, 256, 0, stream>>>(ei, cur, esrc);

  const int gemm_grid = (N_NODES + 63) / 64;  // 1563
  const int aggz_grid = N_NODES / 16;         // 6250 exactly

  for (int l = 0; l < 3; l++) {
    float* s1 = stats + (size_t)(l * 2 + 0) * 2 * NSLICE * 128;
    float* q1 = s1 + NSLICE * 128;
    float* s2 = stats + (size_t)(l * 2 + 1) * 2 * NSLICE * 128;
    float* q2 = s2 + NSLICE * 128;
    if (l == 0) {
      k_aggz<0><<<aggz_grid, 256, 0, stream>>>(xb, off, esrc, eps + l,
                                               nullptr, nullptr, nullptr, nullptr, bufA);
    } else {
      k_aggz<1><<<aggz_grid, 256, 0, stream>>>(bufC, off, esrc, eps + l,
                                               mu2, rs2, g2 + (size_t)(l - 1) * D,
                                               b2 + (size_t)(l - 1) * D, bufA);
    }
    k_gemm<0><<<gemm_grid, 256, 0, stream>>>(bufA, WtB + (size_t)(l * 2 + 0) * D * D, bufB,
                                             nullptr, nullptr, nullptr, nullptr, s1, q1);
    k_bnfin<<<1, 128, 0, stream>>>(s1, q1, mu1, rs1);
    k_gemm<1><<<gemm_grid, 256, 0, stream>>>(bufB, WtB + (size_t)(l * 2 + 1) * D * D, bufC,
                                             mu1, rs1, g1 + (size_t)l * D, b1 + (size_t)l * D,
                                             s2, q2);
    k_bnfin<<<1, 128, 0, stream>>>(s2, q2, mu2, rs2);
  }

  k_readout<<<(N_NODES + RCH - 1) / RCH, 128, 0, stream>>>(bufC, bat, mu2, rs2,
                                                           g2 + 2 * D, b2 + 2 * D,
                                                           out, gsum, gcnt);
  k_gnorm<<<N_GRAPHS, 128, 0, stream>>>(gsum, gcnt, out + (size_t)N_NODES * D);
}

// Round 5
// 703.642 us; speedup vs baseline: 2.6149x; 1.1016x over previous
//
#include <hip/hip_runtime.h>

#define N_NODES 100000
#define N_EDGES 1600000
#define D 128
#define N_GRAPHS 64
#define BN_EPS 1e-5f
#define NSLICE 16

// dst-buckets for the two-phase scatter
#define BNODES 512
#define NBUCK ((N_NODES + BNODES - 1) / BNODES)  // 196
#define EPB 8192
#define NABLK ((N_EDGES + EPB - 1) / EPB)        // 196

typedef short short8 __attribute__((ext_vector_type(8)));
typedef float f32x4 __attribute__((ext_vector_type(4)));

__device__ inline unsigned short f2bf(float f) {
  unsigned int u = __float_as_uint(f);
  u += 0x7fffu + ((u >> 16) & 1);
  return (unsigned short)(u >> 16);
}
__device__ inline float bf2f(unsigned short h) {
  return __uint_as_float(((unsigned int)h) << 16);
}
__device__ inline void unpack8(uint4 u, float* f) {
  f[0] = __uint_as_float(u.x << 16); f[1] = __uint_as_float(u.x & 0xffff0000u);
  f[2] = __uint_as_float(u.y << 16); f[3] = __uint_as_float(u.y & 0xffff0000u);
  f[4] = __uint_as_float(u.z << 16); f[5] = __uint_as_float(u.z & 0xffff0000u);
  f[6] = __uint_as_float(u.w << 16); f[7] = __uint_as_float(u.w & 0xffff0000u);
}
__device__ inline uint4 pack8(const float* f) {
  uint4 u;
  u.x = f2bf(f[0]) | ((unsigned)f2bf(f[1]) << 16);
  u.y = f2bf(f[2]) | ((unsigned)f2bf(f[3]) << 16);
  u.z = f2bf(f[4]) | ((unsigned)f2bf(f[5]) << 16);
  u.w = f2bf(f[6]) | ((unsigned)f2bf(f[7]) << 16);
  return u;
}

// ---------------- input casts / weight prep ----------------
__global__ __launch_bounds__(256) void k_cast(const float* __restrict__ in,
                                              unsigned short* __restrict__ o) {
  long i = ((long)blockIdx.x * blockDim.x + threadIdx.x) * 8;
  if (i >= (long)N_NODES * D) return;
  float4 a = *(const float4*)(in + i);
  float4 b = *(const float4*)(in + i + 4);
  float f[8] = {a.x, a.y, a.z, a.w, b.x, b.y, b.z, b.w};
  *(uint4*)(o + i) = pack8(f);
}

// Wt[mat][n][k] = bf16(W[mat][k][n]); mat = layer*2 + (0:W1,1:W2)
__global__ __launch_bounds__(128) void k_wprep(const float* __restrict__ W1,
                                               const float* __restrict__ W2,
                                               unsigned short* __restrict__ Wt) {
  int m = blockIdx.x;
  int n = blockIdx.y;
  int k = threadIdx.x;
  int l = m >> 1, s = m & 1;
  const float* W = (s == 0 ? W1 : W2) + (size_t)l * D * D;
  Wt[((size_t)m * D + n) * D + k] = f2bf(W[(size_t)k * D + n]);
}

// ---------------- degree histogram + scan ----------------
__global__ void k_hist(const int* __restrict__ dst, int* __restrict__ deg) {
  int i = blockIdx.x * blockDim.x + threadIdx.x;
  if (i < N_EDGES) atomicAdd(&deg[dst[i]], 1);
}

#define SCAN_CH 512
#define SCAN_NB ((N_NODES + SCAN_CH - 1) / SCAN_CH)  // 196

__global__ __launch_bounds__(256) void k_scan1(const int* __restrict__ deg,
                                               int* __restrict__ bsum) {
  __shared__ int ls[256];
  int base = blockIdx.x * SCAN_CH;
  int t = threadIdx.x;
  int s = 0;
  for (int i = t; i < SCAN_CH; i += 256) {
    int idx = base + i;
    if (idx < N_NODES) s += deg[idx];
  }
  ls[t] = s;
  __syncthreads();
  for (int o = 128; o > 0; o >>= 1) {
    if (t < o) ls[t] += ls[t + o];
    __syncthreads();
  }
  if (t == 0) bsum[blockIdx.x] = ls[0];
}

__global__ __launch_bounds__(256) void k_scan2(const int* __restrict__ bsum,
                                               int* __restrict__ bpre) {
  __shared__ int ls[256];
  int t = threadIdx.x;
  int v = (t < SCAN_NB) ? bsum[t] : 0;
  ls[t] = v;
  __syncthreads();
  for (int o = 1; o < 256; o <<= 1) {
    int u = (t >= o) ? ls[t - o] : 0;
    __syncthreads();
    ls[t] += u;
    __syncthreads();
  }
  if (t < SCAN_NB) bpre[t] = ls[t] - v;  // exclusive
}

__global__ __launch_bounds__(256) void k_scan3(const int* __restrict__ deg,
                                               const int* __restrict__ bpre,
                                               int* __restrict__ off,
                                               int* __restrict__ gcur) {
  __shared__ int ls[256];
  int base = blockIdx.x * SCAN_CH;
  int t = threadIdx.x;
  int i0 = base + t * 2;
  int d0 = (i0 < N_NODES) ? deg[i0] : 0;
  int d1 = (i0 + 1 < N_NODES) ? deg[i0 + 1] : 0;
  int s = d0 + d1;
  ls[t] = s;
  __syncthreads();
  for (int o = 1; o < 256; o <<= 1) {
    int u = (t >= o) ? ls[t - o] : 0;
    __syncthreads();
    ls[t] += u;
    __syncthreads();
  }
  int pre = bpre[blockIdx.x] + ls[t] - s;
  if (i0 < N_NODES) off[i0] = pre;
  if (i0 + 1 < N_NODES) off[i0 + 1] = pre + d0;
  if (blockIdx.x == 0 && t == 0) off[N_NODES] = N_EDGES;
  // bucket base cursor: gcur[b] = off[b*BNODES]  (BNODES == SCAN_CH)
  if (t == 0) gcur[blockIdx.x] = pre;
}

// ---------------- two-phase bucketed edge scatter ----------------
// Phase A: bin (src,dst) pairs into dst-bucket-contiguous segments of `pairs`.
__global__ __launch_bounds__(256) void k_scatA(const int* __restrict__ ei,
                                               int* __restrict__ gcur,
                                               int2* __restrict__ pairs) {
  __shared__ int lh[NBUCK];
  __shared__ int lbase[NBUCK];
  const int t = threadIdx.x;
  const int e0 = blockIdx.x * EPB;
  const int e1 = min(e0 + EPB, N_EDGES);
  for (int i = t; i < NBUCK; i += 256) lh[i] = 0;
  __syncthreads();
  for (int e = e0 + t; e < e1; e += 256) {
    int d = ei[N_EDGES + e];
    atomicAdd(&lh[d >> 9], 1);
  }
  __syncthreads();
  for (int i = t; i < NBUCK; i += 256)
    lbase[i] = (lh[i] > 0) ? atomicAdd(&gcur[i], lh[i]) : 0;
  __syncthreads();
  for (int e = e0 + t; e < e1; e += 256) {
    int s = ei[e];
    int d = ei[N_EDGES + e];
    int p = atomicAdd(&lbase[d >> 9], 1);
    pairs[p] = make_int2(s, d);
  }
}

// Phase B: within each bucket, place srcs at exact CSR positions via LDS cursors.
__global__ __launch_bounds__(256) void k_scatB(const int2* __restrict__ pairs,
                                               const int* __restrict__ off,
                                               int* __restrict__ esrc) {
  __shared__ int lcur[BNODES];
  const int t = threadIdx.x;
  const int nb0 = blockIdx.x * BNODES;
  const int nb1 = min(nb0 + BNODES, N_NODES);
  for (int i = t; i < nb1 - nb0; i += 256) lcur[i] = off[nb0 + i];
  __syncthreads();
  const int s0 = off[nb0];
  const int s1 = off[nb1];
  for (int e = s0 + t; e < s1; e += 256) {
    int2 pr = pairs[e];
    int p = atomicAdd(&lcur[pr.y - nb0], 1);
    esrc[p] = pr.x;
  }
}

// ---------------- agg + (1+eps)*h, optional BN+ReLU on gathered rows --------
template <int MODE>
__global__ __launch_bounds__(256) void k_aggz(const unsigned short* __restrict__ h,
                                              const int* __restrict__ off,
                                              const int* __restrict__ esrc,
                                              const float* __restrict__ epsp,
                                              const float* __restrict__ mu,
                                              const float* __restrict__ rs,
                                              const float* __restrict__ gamma,
                                              const float* __restrict__ beta,
                                              unsigned short* __restrict__ z) {
  const int sub = threadIdx.x & 15;
  const int n = blockIdx.x * 16 + (threadIdx.x >> 4);
  const int c = sub << 3;
  float M[8], R[8], G[8], B[8];
  if (MODE == 1) {
#pragma unroll
    for (int j = 0; j < 8; j++) {
      M[j] = mu[c + j]; R[j] = rs[c + j]; G[j] = gamma[c + j]; B[j] = beta[c + j];
    }
  }
  const float e = 1.0f + epsp[0];
  const int o0 = off[n], o1 = off[n + 1];

  float acc[8];
  {
    uint4 u = *(const uint4*)(h + (size_t)n * D + c);
    float f[8];
    unpack8(u, f);
#pragma unroll
    for (int j = 0; j < 8; j++) {
      if (MODE == 1) f[j] = fmaxf(fmaf((f[j] - M[j]) * R[j], G[j], B[j]), 0.f);
      acc[j] = e * f[j];
    }
  }
  int j = o0;
  for (; j + 1 < o1; j += 2) {
    int s0 = esrc[j], s1 = esrc[j + 1];
    uint4 u0 = *(const uint4*)(h + (size_t)s0 * D + c);
    uint4 u1 = *(const uint4*)(h + (size_t)s1 * D + c);
    float f0[8], f1[8];
    unpack8(u0, f0);
    unpack8(u1, f1);
#pragma unroll
    for (int q = 0; q < 8; q++) {
      if (MODE == 1) {
        f0[q] = fmaxf(fmaf((f0[q] - M[q]) * R[q], G[q], B[q]), 0.f);
        f1[q] = fmaxf(fmaf((f1[q] - M[q]) * R[q], G[q], B[q]), 0.f);
      }
      acc[q] += f0[q] + f1[q];
    }
  }
  if (j < o1) {
    uint4 u0 = *(const uint4*)(h + (size_t)esrc[j] * D + c);
    float f0[8];
    unpack8(u0, f0);
#pragma unroll
    for (int q = 0; q < 8; q++) {
      if (MODE == 1) f0[q] = fmaxf(fmaf((f0[q] - M[q]) * R[q], G[q], B[q]), 0.f);
      acc[q] += f0[q];
    }
  }
  *(uint4*)(z + (size_t)n * D + c) = pack8(acc);
}

// ---------------- MFMA GEMM + fused BN column stats ----------------
template <int MODE>
__global__ __launch_bounds__(256) void k_gemm(const unsigned short* __restrict__ A,
                                              const unsigned short* __restrict__ Wt,
                                              unsigned short* __restrict__ out,
                                              const float* __restrict__ mu,
                                              const float* __restrict__ rs,
                                              const float* __restrict__ gamma,
                                              const float* __restrict__ beta,
                                              float* __restrict__ ssum,
                                              float* __restrict__ ssq) {
  __shared__ unsigned short Zs[64 * 136];
  __shared__ float psum[16 * 128];
  __shared__ float psq[16 * 128];
  const int t = threadIdx.x;
  const int row0 = blockIdx.x * 64;

#pragma unroll
  for (int i = 0; i < 4; i++) {
    int q = t + i * 256;
    int r = q >> 4, cb = (q & 15) << 3;
    int grow = row0 + r;
    uint4 u = make_uint4(0u, 0u, 0u, 0u);
    if (grow < N_NODES) {
      u = *(const uint4*)(A + (size_t)grow * D + cb);
      if (MODE == 1) {
        float f[8];
        unpack8(u, f);
#pragma unroll
        for (int jj = 0; jj < 8; jj++)
          f[jj] = fmaxf(fmaf((f[jj] - mu[cb + jj]) * rs[cb + jj], gamma[cb + jj], beta[cb + jj]), 0.f);
        u = pack8(f);
      }
    }
    *(uint4*)&Zs[r * 136 + cb] = u;
  }
  __syncthreads();

  const int lane = t & 63;
  const int wave = t >> 6;
  const int quad = lane >> 4;
  const int lr = lane & 15;
  const int m0 = wave * 16;

  f32x4 acc[8];
#pragma unroll
  for (int i = 0; i < 8; i++) acc[i] = (f32x4){0.f, 0.f, 0.f, 0.f};

#pragma unroll
  for (int kc = 0; kc < 128; kc += 32) {
    short8 af = *(const short8*)&Zs[(m0 + lr) * 136 + kc + quad * 8];
#pragma unroll
    for (int nt = 0; nt < 8; nt++) {
      short8 bf = *(const short8*)(Wt + (size_t)(nt * 16 + lr) * D + kc + quad * 8);
      acc[nt] = __builtin_amdgcn_mfma_f32_16x16x32_bf16(af, bf, acc[nt], 0, 0, 0);
    }
  }

#pragma unroll
  for (int nt = 0; nt < 8; nt++) {
    int col = nt * 16 + lr;
    float s = acc[nt][0] + acc[nt][1] + acc[nt][2] + acc[nt][3];
    float qq = acc[nt][0] * acc[nt][0] + acc[nt][1] * acc[nt][1] +
               acc[nt][2] * acc[nt][2] + acc[nt][3] * acc[nt][3];
    int gi = (wave * 4 + quad) * 128 + col;
    psum[gi] = s;
    psq[gi] = qq;
  }

#pragma unroll
  for (int rr = 0; rr < 4; rr++) {
    int grow = row0 + m0 + quad * 4 + rr;
    if (grow < N_NODES) {
#pragma unroll
      for (int nt = 0; nt < 8; nt++)
        out[(size_t)grow * D + nt * 16 + lr] = f2bf(acc[nt][rr]);
    }
  }

  __syncthreads();
  if (t < 128) {
    float S = 0.f, Q = 0.f;
#pragma unroll
    for (int i = 0; i < 16; i++) {
      S += psum[i * 128 + t];
      Q += psq[i * 128 + t];
    }
    int slice = blockIdx.x & (NSLICE - 1);
    atomicAdd(&ssum[slice * 128 + t], S);
    atomicAdd(&ssq[slice * 128 + t], Q);
  }
}

__global__ void k_bnfin(const float* __restrict__ ssum, const float* __restrict__ ssq,
                        float* __restrict__ mu, float* __restrict__ rs) {
  int f = threadIdx.x;
  float S = 0.f, Q = 0.f;
  for (int i = 0; i < NSLICE; i++) { S += ssum[i * 128 + f]; Q += ssq[i * 128 + f]; }
  float m = S * (1.0f / (float)N_NODES);
  float v = Q * (1.0f / (float)N_NODES) - m * m;
  mu[f] = m;
  rs[f] = rsqrtf(v + BN_EPS);
}

// ---------------- fused BN2+ReLU + node_emb write + graph readout ------------
#define RCH 64
__global__ __launch_bounds__(128) void k_readout(const unsigned short* __restrict__ y,
                                                 const int* __restrict__ batch,
                                                 const float* __restrict__ mu,
                                                 const float* __restrict__ rs,
                                                 const float* __restrict__ gamma,
                                                 const float* __restrict__ beta,
                                                 float* __restrict__ node_out,
                                                 float* __restrict__ gsum,
                                                 int* __restrict__ gcnt) {
  int start = blockIdx.x * RCH;
  int end = min(start + RCH, N_NODES);
  if (start >= end) return;
  int f = threadIdx.x;
  float m = mu[f], r = rs[f], g = gamma[f], b = beta[f];
  float acc = 0.f;
  int cnt = 0;
  int curg = batch[start];
  for (int n = start; n < end; n++) {
    int gg = batch[n];
    float v = fmaxf(fmaf((bf2f(y[(size_t)n * D + f]) - m) * r, g, b), 0.f);
    node_out[(size_t)n * D + f] = v;
    if (gg != curg) {
      atomicAdd(&gsum[curg * D + f], acc);
      if (f == 0) atomicAdd(&gcnt[curg], cnt);
      acc = 0.f; cnt = 0; curg = gg;
    }
    acc += v;
    cnt++;
  }
  atomicAdd(&gsum[curg * D + f], acc);
  if (f == 0) atomicAdd(&gcnt[curg], cnt);
}

__global__ __launch_bounds__(128) void k_gnorm(const float* __restrict__ gsum,
                                               const int* __restrict__ gcnt,
                                               float* __restrict__ out) {
  __shared__ float red[128];
  int g = blockIdx.x, f = threadIdx.x;
  float c = (float)gcnt[g];
  float v = gsum[g * D + f] / fmaxf(c, 1.0f);
  red[f] = v * v;
  __syncthreads();
  for (int o = 64; o > 0; o >>= 1) {
    if (f < o) red[f] += red[f + o];
    __syncthreads();
  }
  float nrm = sqrtf(red[0]);
  out[(size_t)g * D + f] = v / fmaxf(nrm, 1e-12f);
}

extern "C" void kernel_launch(void* const* d_in, const int* in_sizes, int n_in,
                              void* d_out, int out_size, void* d_ws, size_t ws_size,
                              hipStream_t stream) {
  const float* x   = (const float*)d_in[0];
  const int*   ei  = (const int*)d_in[1];
  const int*   bat = (const int*)d_in[2];
  const float* W1  = (const float*)d_in[3];
  const float* g1  = (const float*)d_in[4];
  const float* b1  = (const float*)d_in[5];
  const float* W2  = (const float*)d_in[6];
  const float* g2  = (const float*)d_in[7];
  const float* b2  = (const float*)d_in[8];
  const float* eps = (const float*)d_in[9];
  float* out = (float*)d_out;

  char* w = (char*)d_ws;
  const size_t FEAT_B = (size_t)N_NODES * D * 2;
  unsigned short* xb   = (unsigned short*)w; w += FEAT_B;
  unsigned short* bufA = (unsigned short*)w; w += FEAT_B;
  unsigned short* bufB = (unsigned short*)w; w += FEAT_B;
  unsigned short* bufC = (unsigned short*)w; w += FEAT_B;
  unsigned short* WtB  = (unsigned short*)w; w += (size_t)6 * D * D * 2;
  int* deg  = (int*)w; w += 400016;
  int* off  = (int*)w; w += 400016;
  int* gcur = (int*)w; w += 1024;
  int* esrc = (int*)w; w += (size_t)N_EDGES * 4;
  int* bsum = (int*)w; w += 1024;
  int* bpre = (int*)w; w += 1024;
  float* stats = (float*)w; w += (size_t)6 * 2 * NSLICE * 128 * 4;
  float* mu1  = (float*)w; w += 512;
  float* rs1  = (float*)w; w += 512;
  float* mu2  = (float*)w; w += 512;
  float* rs2  = (float*)w; w += 512;
  float* gsum = (float*)w; w += (size_t)N_GRAPHS * D * 4;
  int* gcnt   = (int*)w; w += 256;
  // pairs buffer (12.8 MB) aliases bufB+bufC region — both unused until the
  // first k_gemm, and k_scatB finishes before that.
  int2* pairs = (int2*)bufB;

  hipMemsetAsync(deg, 0, (size_t)N_NODES * 4, stream);
  hipMemsetAsync(stats, 0, (size_t)6 * 2 * NSLICE * 128 * 4, stream);
  hipMemsetAsync(gsum, 0, (size_t)N_GRAPHS * D * 4 + 256, stream);

  k_cast<<<(N_NODES * D / 8 + 255) / 256, 256, 0, stream>>>(x, xb);
  k_wprep<<<dim3(6, 128), 128, 0, stream>>>(W1, W2, WtB);

  k_hist<<<(N_EDGES + 255) / 256, 256, 0, stream>>>(ei + N_EDGES, deg);
  k_scan1<<<SCAN_NB, 256, 0, stream>>>(deg, bsum);
  k_scan2<<<1, 256, 0, stream>>>(bsum, bpre);
  k_scan3<<<SCAN_NB, 256, 0, stream>>>(deg, bpre, off, gcur);
  k_scatA<<<NABLK, 256, 0, stream>>>(ei, gcur, pairs);
  k_scatB<<<NBUCK, 256, 0, stream>>>(pairs, off, esrc);

  const int gemm_grid = (N_NODES + 63) / 64;
  const int aggz_grid = N_NODES / 16;

  for (int l = 0; l < 3; l++) {
    float* s1 = stats + (size_t)(l * 2 + 0) * 2 * NSLICE * 128;
    float* q1 = s1 + NSLICE * 128;
    float* s2 = stats + (size_t)(l * 2 + 1) * 2 * NSLICE * 128;
    float* q2 = s2 + NSLICE * 128;
    if (l == 0) {
      k_aggz<0><<<aggz_grid, 256, 0, stream>>>(xb, off, esrc, eps + l,
                                               nullptr, nullptr, nullptr, nullptr, bufA);
    } else {
      k_aggz<1><<<aggz_grid, 256, 0, stream>>>(bufC, off, esrc, eps + l,
                                               mu2, rs2, g2 + (size_t)(l - 1) * D,
                                               b2 + (size_t)(l - 1) * D, bufA);
    }
    k_gemm<0><<<gemm_grid, 256, 0, stream>>>(bufA, WtB + (size_t)(l * 2 + 0) * D * D, bufB,
                                             nullptr, nullptr, nullptr, nullptr, s1, q1);
    k_bnfin<<<1, 128, 0, stream>>>(s1, q1, mu1, rs1);
    k_gemm<1><<<gemm_grid, 256, 0, stream>>>(bufB, WtB + (size_t)(l * 2 + 1) * D * D, bufC,
                                             mu1, rs1, g1 + (size_t)l * D, b1 + (size_t)l * D,
                                             s2, q2);
    k_bnfin<<<1, 128, 0, stream>>>(s2, q2, mu2, rs2);
  }

  k_readout<<<(N_NODES + RCH - 1) / RCH, 128, 0, stream>>>(bufC, bat, mu2, rs2,
                                                           g2 + 2 * D, b2 + 2 * D,
                                                           out, gsum, gcnt);
  k_gnorm<<<N_GRAPHS, 128, 0, stream>>>(gsum, gcnt, out + (size_t)N_NODES * D);
}

// Round 6
// 654.864 us; speedup vs baseline: 2.8097x; 1.0745x over previous
//
#include <hip/hip_runtime.h>

#define N_NODES 100000
#define N_EDGES 1600000
#define D 128
#define N_GRAPHS 64
#define BN_EPS 1e-5f
#define NSLICE 16

// dst-buckets for the two-phase scatter
#define BNODES 256
#define NBUCK ((N_NODES + BNODES - 1) / BNODES)  // 391
#define EPB 8192
#define NABLK ((N_EDGES + EPB - 1) / EPB)        // 196

typedef short short8 __attribute__((ext_vector_type(8)));
typedef float f32x4 __attribute__((ext_vector_type(4)));

__device__ inline unsigned short f2bf(float f) {
  unsigned int u = __float_as_uint(f);
  u += 0x7fffu + ((u >> 16) & 1);
  return (unsigned short)(u >> 16);
}
__device__ inline float bf2f(unsigned short h) {
  return __uint_as_float(((unsigned int)h) << 16);
}
__device__ inline void unpack8(uint4 u, float* f) {
  f[0] = __uint_as_float(u.x << 16); f[1] = __uint_as_float(u.x & 0xffff0000u);
  f[2] = __uint_as_float(u.y << 16); f[3] = __uint_as_float(u.y & 0xffff0000u);
  f[4] = __uint_as_float(u.z << 16); f[5] = __uint_as_float(u.z & 0xffff0000u);
  f[6] = __uint_as_float(u.w << 16); f[7] = __uint_as_float(u.w & 0xffff0000u);
}
__device__ inline uint4 pack8(const float* f) {
  uint4 u;
  u.x = f2bf(f[0]) | ((unsigned)f2bf(f[1]) << 16);
  u.y = f2bf(f[2]) | ((unsigned)f2bf(f[3]) << 16);
  u.z = f2bf(f[4]) | ((unsigned)f2bf(f[5]) << 16);
  u.w = f2bf(f[6]) | ((unsigned)f2bf(f[7]) << 16);
  return u;
}

// ---------------- input casts / weight prep ----------------
__global__ __launch_bounds__(256) void k_cast(const float* __restrict__ in,
                                              unsigned short* __restrict__ o) {
  long i = ((long)blockIdx.x * blockDim.x + threadIdx.x) * 8;
  if (i >= (long)N_NODES * D) return;
  float4 a = *(const float4*)(in + i);
  float4 b = *(const float4*)(in + i + 4);
  float f[8] = {a.x, a.y, a.z, a.w, b.x, b.y, b.z, b.w};
  *(uint4*)(o + i) = pack8(f);
}

// Wt[mat][n][k] = bf16(W[mat][k][n]); mat = layer*2 + (0:W1,1:W2)
__global__ __launch_bounds__(128) void k_wprep(const float* __restrict__ W1,
                                               const float* __restrict__ W2,
                                               unsigned short* __restrict__ Wt) {
  int m = blockIdx.x;
  int n = blockIdx.y;
  int k = threadIdx.x;
  int l = m >> 1, s = m & 1;
  const float* W = (s == 0 ? W1 : W2) + (size_t)l * D * D;
  Wt[((size_t)m * D + n) * D + k] = f2bf(W[(size_t)k * D + n]);
}

// ---------------- bucket histogram + scan ----------------
__global__ __launch_bounds__(256) void k_histb(const int* __restrict__ dst,
                                               int* __restrict__ ecount) {
  __shared__ int lh[NBUCK];
  const int t = threadIdx.x;
  const int e0 = blockIdx.x * EPB;
  const int e1 = min(e0 + EPB, N_EDGES);
  for (int i = t; i < NBUCK; i += 256) lh[i] = 0;
  __syncthreads();
  for (int e = e0 + t; e < e1; e += 256) atomicAdd(&lh[dst[e] >> 8], 1);
  __syncthreads();
  for (int i = t; i < NBUCK; i += 256)
    if (lh[i]) atomicAdd(&ecount[i], lh[i]);
}

__global__ __launch_bounds__(512) void k_scanb(const int* __restrict__ ecount,
                                               int* __restrict__ ebase,
                                               int* __restrict__ gcur) {
  __shared__ int ls[512];
  int t = threadIdx.x;
  int v = (t < NBUCK) ? ecount[t] : 0;
  ls[t] = v;
  __syncthreads();
  for (int o = 1; o < 512; o <<= 1) {
    int u = (t >= o) ? ls[t - o] : 0;
    __syncthreads();
    ls[t] += u;
    __syncthreads();
  }
  int ex = ls[t] - v;
  if (t < NBUCK) { ebase[t] = ex; gcur[t] = ex; }
  if (t == 0) ebase[NBUCK] = N_EDGES;
}

// ---------------- two-phase bucketed edge scatter ----------------
__global__ __launch_bounds__(256) void k_scatA(const int* __restrict__ ei,
                                               int* __restrict__ gcur,
                                               int2* __restrict__ pairs) {
  __shared__ int lh[NBUCK];
  __shared__ int lbase[NBUCK];
  const int t = threadIdx.x;
  const int e0 = blockIdx.x * EPB;
  const int e1 = min(e0 + EPB, N_EDGES);
  for (int i = t; i < NBUCK; i += 256) lh[i] = 0;
  __syncthreads();
  for (int e = e0 + t; e < e1; e += 256) atomicAdd(&lh[ei[N_EDGES + e] >> 8], 1);
  __syncthreads();
  for (int i = t; i < NBUCK; i += 256)
    lbase[i] = (lh[i] > 0) ? atomicAdd(&gcur[i], lh[i]) : 0;
  __syncthreads();
  for (int e = e0 + t; e < e1; e += 256) {
    int s = ei[e];
    int d = ei[N_EDGES + e];
    int p = atomicAdd(&lbase[d >> 8], 1);
    pairs[p] = make_int2(s, d);
  }
}

// Phase B: per bucket, build per-node CSR offsets in LDS and place srcs.
__global__ __launch_bounds__(256) void k_scatB(const int2* __restrict__ pairs,
                                               const int* __restrict__ ebase,
                                               int* __restrict__ off,
                                               int* __restrict__ esrc) {
  __shared__ int lcnt[BNODES];
  __shared__ int ls[256];
  const int t = threadIdx.x;
  const int b = blockIdx.x;
  const int nb0 = b * BNODES;
  const int nn = min(BNODES, N_NODES - nb0);
  const int s0 = ebase[b], s1 = ebase[b + 1];
  if (t < nn) lcnt[t] = 0;
  __syncthreads();
  for (int e = s0 + t; e < s1; e += 256) atomicAdd(&lcnt[pairs[e].y - nb0], 1);
  __syncthreads();
  int c0 = (t < nn) ? lcnt[t] : 0;
  ls[t] = c0;
  __syncthreads();
  for (int o = 1; o < 256; o <<= 1) {
    int u = (t >= o) ? ls[t - o] : 0;
    __syncthreads();
    ls[t] += u;
    __syncthreads();
  }
  int pre = ls[t] - c0;  // exclusive prefix within bucket
  if (t < nn) {
    off[nb0 + t] = s0 + pre;
    lcnt[t] = s0 + pre;  // reuse as cursor
  }
  __syncthreads();
  for (int e = s0 + t; e < s1; e += 256) {
    int2 p = pairs[e];
    int pos = atomicAdd(&lcnt[p.y - nb0], 1);
    esrc[pos] = p.x;
  }
  if (b == 0 && t == 0) off[N_NODES] = N_EDGES;
}

// ---------------- agg + (1+eps)*h: ONE WAVE PER NODE, 2 feats/lane ----------
// MODE 1 applies h = relu(y*sc + tb) to every gathered row on the fly.
template <int MODE>
__global__ __launch_bounds__(256) void k_aggz(const unsigned short* __restrict__ h,
                                              const int* __restrict__ off,
                                              const int* __restrict__ esrc,
                                              const float* __restrict__ epsp,
                                              const float* __restrict__ sc,
                                              const float* __restrict__ tb,
                                              unsigned short* __restrict__ z) {
  const int lane = threadIdx.x & 63;
  const int n = blockIdx.x * 4 + (threadIdx.x >> 6);
  const int c = lane << 1;
  float S0 = 0.f, S1 = 0.f, T0 = 0.f, T1 = 0.f;
  if (MODE == 1) { S0 = sc[c]; S1 = sc[c + 1]; T0 = tb[c]; T1 = tb[c + 1]; }
  const float e = 1.0f + epsp[0];
  const int o0 = off[n], o1 = off[n + 1];

  float a0, a1;
  {
    unsigned int u = *(const unsigned int*)(h + (size_t)n * D + c);
    float lo = __uint_as_float(u << 16);
    float hi = __uint_as_float(u & 0xffff0000u);
    if (MODE == 1) {
      lo = fmaxf(fmaf(lo, S0, T0), 0.f);
      hi = fmaxf(fmaf(hi, S1, T1), 0.f);
    }
    a0 = e * lo;
    a1 = e * hi;
  }

  int j = o0;
  for (; j + 3 < o1; j += 4) {
    int i0 = esrc[j], i1 = esrc[j + 1], i2 = esrc[j + 2], i3 = esrc[j + 3];
    unsigned int u0 = *(const unsigned int*)(h + (size_t)i0 * D + c);
    unsigned int u1 = *(const unsigned int*)(h + (size_t)i1 * D + c);
    unsigned int u2 = *(const unsigned int*)(h + (size_t)i2 * D + c);
    unsigned int u3 = *(const unsigned int*)(h + (size_t)i3 * D + c);
    float l0 = __uint_as_float(u0 << 16), h0 = __uint_as_float(u0 & 0xffff0000u);
    float l1 = __uint_as_float(u1 << 16), h1 = __uint_as_float(u1 & 0xffff0000u);
    float l2 = __uint_as_float(u2 << 16), h2 = __uint_as_float(u2 & 0xffff0000u);
    float l3 = __uint_as_float(u3 << 16), h3 = __uint_as_float(u3 & 0xffff0000u);
    if (MODE == 1) {
      l0 = fmaxf(fmaf(l0, S0, T0), 0.f); h0 = fmaxf(fmaf(h0, S1, T1), 0.f);
      l1 = fmaxf(fmaf(l1, S0, T0), 0.f); h1 = fmaxf(fmaf(h1, S1, T1), 0.f);
      l2 = fmaxf(fmaf(l2, S0, T0), 0.f); h2 = fmaxf(fmaf(h2, S1, T1), 0.f);
      l3 = fmaxf(fmaf(l3, S0, T0), 0.f); h3 = fmaxf(fmaf(h3, S1, T1), 0.f);
    }
    a0 += (l0 + l1) + (l2 + l3);
    a1 += (h0 + h1) + (h2 + h3);
  }
  for (; j < o1; j++) {
    unsigned int u0 = *(const unsigned int*)(h + (size_t)esrc[j] * D + c);
    float l0 = __uint_as_float(u0 << 16), h0 = __uint_as_float(u0 & 0xffff0000u);
    if (MODE == 1) {
      l0 = fmaxf(fmaf(l0, S0, T0), 0.f);
      h0 = fmaxf(fmaf(h0, S1, T1), 0.f);
    }
    a0 += l0;
    a1 += h0;
  }
  unsigned int pk = (unsigned int)f2bf(a0) | ((unsigned int)f2bf(a1) << 16);
  *(unsigned int*)(z + (size_t)n * D + c) = pk;
}

// ---------------- MFMA GEMM + fused BN column stats ----------------
template <int MODE>
__global__ __launch_bounds__(256) void k_gemm(const unsigned short* __restrict__ A,
                                              const unsigned short* __restrict__ Wt,
                                              unsigned short* __restrict__ out,
                                              const float* __restrict__ sc,
                                              const float* __restrict__ tb,
                                              float* __restrict__ ssum,
                                              float* __restrict__ ssq) {
  __shared__ unsigned short Zs[64 * 136];
  __shared__ float psum[16 * 128];
  __shared__ float psq[16 * 128];
  const int t = threadIdx.x;
  const int row0 = blockIdx.x * 64;

#pragma unroll
  for (int i = 0; i < 4; i++) {
    int q = t + i * 256;
    int r = q >> 4, cb = (q & 15) << 3;
    int grow = row0 + r;
    uint4 u = make_uint4(0u, 0u, 0u, 0u);
    if (grow < N_NODES) {
      u = *(const uint4*)(A + (size_t)grow * D + cb);
      if (MODE == 1) {
        float f[8];
        unpack8(u, f);
#pragma unroll
        for (int jj = 0; jj < 8; jj++)
          f[jj] = fmaxf(fmaf(f[jj], sc[cb + jj], tb[cb + jj]), 0.f);
        u = pack8(f);
      }
    }
    *(uint4*)&Zs[r * 136 + cb] = u;
  }
  __syncthreads();

  const int lane = t & 63;
  const int wave = t >> 6;
  const int quad = lane >> 4;
  const int lr = lane & 15;
  const int m0 = wave * 16;

  f32x4 acc[8];
#pragma unroll
  for (int i = 0; i < 8; i++) acc[i] = (f32x4){0.f, 0.f, 0.f, 0.f};

#pragma unroll
  for (int kc = 0; kc < 128; kc += 32) {
    short8 af = *(const short8*)&Zs[(m0 + lr) * 136 + kc + quad * 8];
#pragma unroll
    for (int nt = 0; nt < 8; nt++) {
      short8 bf = *(const short8*)(Wt + (size_t)(nt * 16 + lr) * D + kc + quad * 8);
      acc[nt] = __builtin_amdgcn_mfma_f32_16x16x32_bf16(af, bf, acc[nt], 0, 0, 0);
    }
  }

#pragma unroll
  for (int nt = 0; nt < 8; nt++) {
    int col = nt * 16 + lr;
    float s = acc[nt][0] + acc[nt][1] + acc[nt][2] + acc[nt][3];
    float qq = acc[nt][0] * acc[nt][0] + acc[nt][1] * acc[nt][1] +
               acc[nt][2] * acc[nt][2] + acc[nt][3] * acc[nt][3];
    int gi = (wave * 4 + quad) * 128 + col;
    psum[gi] = s;
    psq[gi] = qq;
  }

#pragma unroll
  for (int rr = 0; rr < 4; rr++) {
    int grow = row0 + m0 + quad * 4 + rr;
    if (grow < N_NODES) {
#pragma unroll
      for (int nt = 0; nt < 8; nt++)
        out[(size_t)grow * D + nt * 16 + lr] = f2bf(acc[nt][rr]);
    }
  }

  __syncthreads();
  if (t < 128) {
    float S = 0.f, Q = 0.f;
#pragma unroll
    for (int i = 0; i < 16; i++) {
      S += psum[i * 128 + t];
      Q += psq[i * 128 + t];
    }
    int slice = blockIdx.x & (NSLICE - 1);
    atomicAdd(&ssum[slice * 128 + t], S);
    atomicAdd(&ssq[slice * 128 + t], Q);
  }
}

// fold stats -> affine BN coeffs: bn(y) = y*sc + tb
__global__ void k_bnfin(const float* __restrict__ ssum, const float* __restrict__ ssq,
                        const float* __restrict__ gamma, const float* __restrict__ beta,
                        float* __restrict__ sc, float* __restrict__ tb) {
  int f = threadIdx.x;
  float S = 0.f, Q = 0.f;
  for (int i = 0; i < NSLICE; i++) { S += ssum[i * 128 + f]; Q += ssq[i * 128 + f]; }
  float m = S * (1.0f / (float)N_NODES);
  float v = Q * (1.0f / (float)N_NODES) - m * m;
  float r = rsqrtf(v + BN_EPS);
  float s = r * gamma[f];
  sc[f] = s;
  tb[f] = beta[f] - m * s;
}

// ---------------- fused BN2+ReLU + node_emb write + graph readout ------------
#define RCH 64
__global__ __launch_bounds__(128) void k_readout(const unsigned short* __restrict__ y,
                                                 const int* __restrict__ batch,
                                                 const float* __restrict__ sc,
                                                 const float* __restrict__ tb,
                                                 float* __restrict__ node_out,
                                                 float* __restrict__ gsum,
                                                 int* __restrict__ gcnt) {
  int start = blockIdx.x * RCH;
  int end = min(start + RCH, N_NODES);
  if (start >= end) return;
  int f = threadIdx.x;
  float s = sc[f], tt = tb[f];
  float acc = 0.f;
  int cnt = 0;
  int curg = batch[start];
  for (int n = start; n < end; n++) {
    int gg = batch[n];
    float v = fmaxf(fmaf(bf2f(y[(size_t)n * D + f]), s, tt), 0.f);
    node_out[(size_t)n * D + f] = v;
    if (gg != curg) {
      atomicAdd(&gsum[curg * D + f], acc);
      if (f == 0) atomicAdd(&gcnt[curg], cnt);
      acc = 0.f; cnt = 0; curg = gg;
    }
    acc += v;
    cnt++;
  }
  atomicAdd(&gsum[curg * D + f], acc);
  if (f == 0) atomicAdd(&gcnt[curg], cnt);
}

__global__ __launch_bounds__(128) void k_gnorm(const float* __restrict__ gsum,
                                               const int* __restrict__ gcnt,
                                               float* __restrict__ out) {
  __shared__ float red[128];
  int g = blockIdx.x, f = threadIdx.x;
  float c = (float)gcnt[g];
  float v = gsum[g * D + f] / fmaxf(c, 1.0f);
  red[f] = v * v;
  __syncthreads();
  for (int o = 64; o > 0; o >>= 1) {
    if (f < o) red[f] += red[f + o];
    __syncthreads();
  }
  float nrm = sqrtf(red[0]);
  out[(size_t)g * D + f] = v / fmaxf(nrm, 1e-12f);
}

extern "C" void kernel_launch(void* const* d_in, const int* in_sizes, int n_in,
                              void* d_out, int out_size, void* d_ws, size_t ws_size,
                              hipStream_t stream) {
  const float* x   = (const float*)d_in[0];
  const int*   ei  = (const int*)d_in[1];
  const int*   bat = (const int*)d_in[2];
  const float* W1  = (const float*)d_in[3];
  const float* g1  = (const float*)d_in[4];
  const float* b1  = (const float*)d_in[5];
  const float* W2  = (const float*)d_in[6];
  const float* g2  = (const float*)d_in[7];
  const float* b2  = (const float*)d_in[8];
  const float* eps = (const float*)d_in[9];
  float* out = (float*)d_out;

  char* w = (char*)d_ws;
  const size_t FEAT_B = (size_t)N_NODES * D * 2;
  unsigned short* xb   = (unsigned short*)w; w += FEAT_B;
  unsigned short* bufA = (unsigned short*)w; w += FEAT_B;
  unsigned short* bufB = (unsigned short*)w; w += FEAT_B;
  unsigned short* bufC = (unsigned short*)w; w += FEAT_B;
  unsigned short* WtB  = (unsigned short*)w; w += (size_t)6 * D * D * 2;
  int* off   = (int*)w; w += 400016;
  int* ebase = (int*)w; w += 2048;
  int* gcur  = (int*)w; w += 2048;
  int* esrc  = (int*)w; w += (size_t)N_EDGES * 4;
  float* sc1 = (float*)w; w += 512;
  float* tb1 = (float*)w; w += 512;
  float* sc2 = (float*)w; w += 512;
  float* tb2 = (float*)w; w += 512;
  // zero-init region (single memset): ecount | stats | gsum | gcnt
  char* zreg = w;
  int* ecount  = (int*)w; w += 2048;
  float* stats = (float*)w; w += (size_t)6 * 2 * NSLICE * 128 * 4;  // 96 KB
  float* gsum  = (float*)w; w += (size_t)N_GRAPHS * D * 4;
  int* gcnt    = (int*)w; w += 256;
  size_t zbytes = (size_t)((char*)w - zreg);
  // pairs (12.8 MB) aliases bufB — unused until first k_gemm, scatB done by then.
  int2* pairs = (int2*)bufB;

  hipMemsetAsync(zreg, 0, zbytes, stream);

  k_cast<<<(N_NODES * D / 8 + 255) / 256, 256, 0, stream>>>(x, xb);
  k_wprep<<<dim3(6, 128), 128, 0, stream>>>(W1, W2, WtB);

  k_histb<<<NABLK, 256, 0, stream>>>(ei + N_EDGES, ecount);
  k_scanb<<<1, 512, 0, stream>>>(ecount, ebase, gcur);
  k_scatA<<<NABLK, 256, 0, stream>>>(ei, gcur, pairs);
  k_scatB<<<NBUCK, 256, 0, stream>>>(pairs, ebase, off, esrc);

  const int gemm_grid = (N_NODES + 63) / 64;  // 1563
  const int aggz_grid = N_NODES / 4;          // 25000 exactly

  for (int l = 0; l < 3; l++) {
    float* s1 = stats + (size_t)(l * 2 + 0) * 2 * NSLICE * 128;
    float* q1 = s1 + NSLICE * 128;
    float* s2 = stats + (size_t)(l * 2 + 1) * 2 * NSLICE * 128;
    float* q2 = s2 + NSLICE * 128;
    if (l == 0) {
      k_aggz<0><<<aggz_grid, 256, 0, stream>>>(xb, off, esrc, eps + l,
                                               nullptr, nullptr, bufA);
    } else {
      k_aggz<1><<<aggz_grid, 256, 0, stream>>>(bufC, off, esrc, eps + l,
                                               sc2, tb2, bufA);
    }
    k_gemm<0><<<gemm_grid, 256, 0, stream>>>(bufA, WtB + (size_t)(l * 2 + 0) * D * D, bufB,
                                             nullptr, nullptr, s1, q1);
    k_bnfin<<<1, 128, 0, stream>>>(s1, q1, g1 + (size_t)l * D, b1 + (size_t)l * D, sc1, tb1);
    k_gemm<1><<<gemm_grid, 256, 0, stream>>>(bufB, WtB + (size_t)(l * 2 + 1) * D * D, bufC,
                                             sc1, tb1, s2, q2);
    k_bnfin<<<1, 128, 0, stream>>>(s2, q2, g2 + (size_t)l * D, b2 + (size_t)l * D, sc2, tb2);
  }

  k_readout<<<(N_NODES + RCH - 1) / RCH, 128, 0, stream>>>(bufC, bat, sc2, tb2,
                                                           out, gsum, gcnt);
  k_gnorm<<<N_GRAPHS, 128, 0, stream>>>(gsum, gcnt, out + (size_t)N_NODES * D);
}